// Round 2
// baseline (2143.628 us; speedup 1.0000x reference)
//
#include <hip/hip_runtime.h>
#include <hip/hip_bf16.h>

#define N_NODES 200000
#define N_EDGES 500000
#define F_IN    165
#define HIDDEN  384
#define F_OUT   2

typedef unsigned short ushort_t;
typedef unsigned int   uint_t;

__device__ __forceinline__ float bf2f(uint_t u) {
    return __uint_as_float(u << 16);
}
__device__ __forceinline__ ushort_t f2bf(float x) {
    uint_t b = __float_as_uint(x);
    return (ushort_t)((b + 0x7FFFu + ((b >> 16) & 1u)) >> 16);  // RNE
}

// ---------------------------------------------------------------------------
// degree count (in-degree via col), int atomics into `cnt`
// ---------------------------------------------------------------------------
__global__ void count_kernel(const int* __restrict__ col, int* __restrict__ cnt, int E) {
    int e = blockIdx.x * blockDim.x + threadIdx.x;
    if (e < E) atomicAdd(&cnt[col[e]], 1);
}

__global__ void dinv_kernel(const int* __restrict__ cnt, float* __restrict__ dinv, int n) {
    int i = blockIdx.x * blockDim.x + threadIdx.x;
    if (i < n) dinv[i] = rsqrtf((float)(cnt[i] + 1));   // +1 self loop
}

// ---------------------------------------------------------------------------
// single-block exclusive scan: reads cnt (in cnt_cursor), writes ptr[0..N],
// and rewrites cnt_cursor[i] = ptr[i] (scatter cursor).
// ---------------------------------------------------------------------------
#define SCAN_T 1024
__global__ __launch_bounds__(SCAN_T) void scan_kernel(int* __restrict__ cnt_cursor,
                                                      int* __restrict__ ptr, int N) {
    __shared__ int sh[SCAN_T];
    int t = threadIdx.x;
    int chunk = (N + SCAN_T - 1) / SCAN_T;
    int s = t * chunk;
    int epos = min(s + chunk, N);
    int sum = 0;
    for (int j = s; j < epos; ++j) sum += cnt_cursor[j];
    sh[t] = sum;
    __syncthreads();
    for (int off = 1; off < SCAN_T; off <<= 1) {
        int v = (t >= off) ? sh[t - off] : 0;
        __syncthreads();
        sh[t] += v;
        __syncthreads();
    }
    int run = (t == 0) ? 0 : sh[t - 1];
    for (int j = s; j < epos; ++j) {
        int c = cnt_cursor[j];
        ptr[j] = run;
        cnt_cursor[j] = run;   // cursor = start slot
        run += c;
    }
    if (epos == N) ptr[N] = run;   // all qualifying threads write total E
}

// ---------------------------------------------------------------------------
// scatter edges into CSR-by-col order; nrm = dinv[r]*dinv[c]
// ---------------------------------------------------------------------------
__global__ void scatter_kernel(const int* __restrict__ row, const int* __restrict__ col,
                               const float* __restrict__ dinv,
                               int* __restrict__ cursor,
                               int* __restrict__ row_srt, float* __restrict__ nrm_srt, int E) {
    int e = blockIdx.x * blockDim.x + threadIdx.x;
    if (e >= E) return;
    int r = row[e], c = col[e];
    int pos = atomicAdd(&cursor[c], 1);
    row_srt[pos] = r;
    nrm_srt[pos] = dinv[r] * dinv[c];
}

// ---------------------------------------------------------------------------
// agg for x (fp32 in, F=165) -> bf16 out. one wave per node.
// out[i] = dinv[i]^2 * x[i] + sum_e nrm_e * x[row_e]
// ---------------------------------------------------------------------------
__global__ __launch_bounds__(256) void agg165_kernel(
        const float* __restrict__ X, const float* __restrict__ dinv,
        const int* __restrict__ ptr, const int* __restrict__ row_srt,
        const float* __restrict__ nrm_srt, ushort_t* __restrict__ out, int N) {
    int w    = (blockIdx.x * blockDim.x + threadIdx.x) >> 6;
    int lane = threadIdx.x & 63;
    if (w >= N) return;
    float d2 = dinv[w]; d2 *= d2;
    int f0 = lane, f1 = lane + 64, f2 = lane + 128;
    const float* xs = X + (size_t)w * F_IN;
    float a0 = xs[f0] * d2;
    float a1 = xs[f1] * d2;
    float a2 = (f2 < F_IN) ? xs[f2] * d2 : 0.0f;
    int e0 = ptr[w], e1 = ptr[w + 1];
    for (int e = e0; e < e1; ++e) {
        int r = row_srt[e];
        float wg = nrm_srt[e];
        const float* xr = X + (size_t)r * F_IN;
        a0 = fmaf(xr[f0], wg, a0);
        a1 = fmaf(xr[f1], wg, a1);
        if (f2 < F_IN) a2 = fmaf(xr[f2], wg, a2);
    }
    ushort_t* o = out + (size_t)w * F_IN;
    o[f0] = f2bf(a0);
    o[f1] = f2bf(a1);
    if (f2 < F_IN) o[f2] = f2bf(a2);
}

// ---------------------------------------------------------------------------
// agg for bf16 H (F=384) -> bf16 out. one wave per node, 6 feats/lane.
// ---------------------------------------------------------------------------
__global__ __launch_bounds__(256) void agg384_kernel(
        const ushort_t* __restrict__ H, const float* __restrict__ dinv,
        const int* __restrict__ ptr, const int* __restrict__ row_srt,
        const float* __restrict__ nrm_srt, ushort_t* __restrict__ out, int N) {
    int w    = (blockIdx.x * blockDim.x + threadIdx.x) >> 6;
    int lane = threadIdx.x & 63;
    if (w >= N) return;
    float d2 = dinv[w]; d2 *= d2;
    const uint_t* self = (const uint_t*)(H + (size_t)w * HIDDEN);
    float ax[3], ay[3];
    #pragma unroll
    for (int j = 0; j < 3; ++j) {
        uint_t u = self[lane + 64 * j];
        ax[j] = bf2f(u & 0xFFFFu) * d2;
        ay[j] = bf2f(u >> 16) * d2;
    }
    int e0 = ptr[w], e1 = ptr[w + 1];
    for (int e = e0; e < e1; ++e) {
        int r = row_srt[e];
        float wg = nrm_srt[e];
        const uint_t* hr = (const uint_t*)(H + (size_t)r * HIDDEN);
        #pragma unroll
        for (int j = 0; j < 3; ++j) {
            uint_t u = hr[lane + 64 * j];
            ax[j] = fmaf(bf2f(u & 0xFFFFu), wg, ax[j]);
            ay[j] = fmaf(bf2f(u >> 16), wg, ay[j]);
        }
    }
    uint_t* o = (uint_t*)(out + (size_t)w * HIDDEN);
    #pragma unroll
    for (int j = 0; j < 3; ++j)
        o[lane + 64 * j] = (uint_t)f2bf(ax[j]) | ((uint_t)f2bf(ay[j]) << 16);
}

// ---------------------------------------------------------------------------
// tiled GEMM: C[M,N] = relu(A[M,K](bf16) @ B[K,N](f32) + bias), C bf16
// 64x64 tile, BK=16, 256 threads, 4x4 microtile.
// ---------------------------------------------------------------------------
#define TM 64
#define TN 64
#define TK 16

template<bool RELU>
__global__ __launch_bounds__(256) void gemm_bias_kernel(
        const ushort_t* __restrict__ A, const float* __restrict__ B,
        const float* __restrict__ bias, ushort_t* __restrict__ C,
        int M, int N, int K) {
    __shared__ float As[TK][TM + 4];
    __shared__ float Bs[TK][TN];

    int tid = threadIdx.x;
    int bm = blockIdx.x * TM;
    int bn = blockIdx.y * TN;
    int tx = tid & 15;
    int ty = tid >> 4;

    int ar = tid >> 2;
    int ak = (tid & 3) * 4;
    int bk = tid >> 4;
    int bc = (tid & 15) * 4;

    const ushort_t* Arow = A + (size_t)(bm + ar) * K;

    float acc[4][4] = {};

    for (int k0 = 0; k0 < K; k0 += TK) {
        #pragma unroll
        for (int i = 0; i < 4; ++i) {
            int k = k0 + ak + i;
            As[ak + i][ar] = (k < K) ? bf2f((uint_t)Arow[k]) : 0.0f;
        }
        float4 bv = make_float4(0.f, 0.f, 0.f, 0.f);
        if (k0 + bk < K)
            bv = *reinterpret_cast<const float4*>(B + (size_t)(k0 + bk) * N + bn + bc);
        *reinterpret_cast<float4*>(&Bs[bk][bc]) = bv;
        __syncthreads();

        #pragma unroll
        for (int kk = 0; kk < TK; ++kk) {
            float4 av = *reinterpret_cast<const float4*>(&As[kk][ty * 4]);
            float4 bw = *reinterpret_cast<const float4*>(&Bs[kk][tx * 4]);
            float a[4] = {av.x, av.y, av.z, av.w};
            float b[4] = {bw.x, bw.y, bw.z, bw.w};
            #pragma unroll
            for (int i = 0; i < 4; ++i)
                #pragma unroll
                for (int j = 0; j < 4; ++j)
                    acc[i][j] = fmaf(a[i], b[j], acc[i][j]);
        }
        __syncthreads();
    }

    float4 bb = *reinterpret_cast<const float4*>(bias + bn + tx * 4);
    float bias4[4] = {bb.x, bb.y, bb.z, bb.w};
    #pragma unroll
    for (int i = 0; i < 4; ++i) {
        int rowi = bm + ty * 4 + i;
        ushort4 o;
        float v;
        v = acc[i][0] + bias4[0]; if (RELU) v = fmaxf(v, 0.f); o.x = f2bf(v);
        v = acc[i][1] + bias4[1]; if (RELU) v = fmaxf(v, 0.f); o.y = f2bf(v);
        v = acc[i][2] + bias4[2]; if (RELU) v = fmaxf(v, 0.f); o.z = f2bf(v);
        v = acc[i][3] + bias4[3]; if (RELU) v = fmaxf(v, 0.f); o.w = f2bf(v);
        *reinterpret_cast<ushort4*>(C + (size_t)rowi * N + bn + tx * 4) = o;
    }
}

// ---------------------------------------------------------------------------
// G[M,2] = A[M,384](bf16) @ W[384,2](f32) ; wave per row
// ---------------------------------------------------------------------------
__global__ __launch_bounds__(256) void gemm_n2_kernel(
        const ushort_t* __restrict__ A, const float* __restrict__ W,
        float* __restrict__ G, int M) {
    int w    = (blockIdx.x * blockDim.x + threadIdx.x) >> 6;
    int lane = threadIdx.x & 63;
    if (w >= M) return;
    const uint_t* a = (const uint_t*)(A + (size_t)w * HIDDEN);
    float s0 = 0.f, s1 = 0.f;
    #pragma unroll
    for (int j = 0; j < 3; ++j) {
        int f2 = lane + 64 * j;
        uint_t u = a[f2];
        float alo = bf2f(u & 0xFFFFu), ahi = bf2f(u >> 16);
        int k = f2 * 2;
        s0 = fmaf(alo, W[k * 2 + 0], s0);
        s1 = fmaf(alo, W[k * 2 + 1], s1);
        s0 = fmaf(ahi, W[k * 2 + 2], s0);
        s1 = fmaf(ahi, W[k * 2 + 3], s1);
    }
    #pragma unroll
    for (int off = 32; off; off >>= 1) {
        s0 += __shfl_down(s0, off);
        s1 += __shfl_down(s1, off);
    }
    if (lane == 0) { G[(size_t)w * 2] = s0; G[(size_t)w * 2 + 1] = s1; }
}

// ---------------------------------------------------------------------------
// final: out[i,:] = dinv[i]^2*G[i,:] + sum_e nrm_e*G[row_e,:] + b3
// one thread per node (avg in-degree 2.5)
// ---------------------------------------------------------------------------
__global__ void out_kernel(const float* __restrict__ G, const float* __restrict__ dinv,
                           const int* __restrict__ ptr, const int* __restrict__ row_srt,
                           const float* __restrict__ nrm_srt, const float* __restrict__ b3,
                           float* __restrict__ out, int N) {
    int i = blockIdx.x * blockDim.x + threadIdx.x;
    if (i >= N) return;
    float d2 = dinv[i]; d2 *= d2;
    float a0 = G[(size_t)i * 2 + 0] * d2 + b3[0];
    float a1 = G[(size_t)i * 2 + 1] * d2 + b3[1];
    int e0 = ptr[i], e1 = ptr[i + 1];
    for (int e = e0; e < e1; ++e) {
        int r = row_srt[e];
        float wg = nrm_srt[e];
        a0 = fmaf(G[(size_t)r * 2 + 0], wg, a0);
        a1 = fmaf(G[(size_t)r * 2 + 1], wg, a1);
    }
    out[(size_t)i * 2 + 0] = a0;
    out[(size_t)i * 2 + 1] = a1;
}

// ---------------------------------------------------------------------------
extern "C" void kernel_launch(void* const* d_in, const int* in_sizes, int n_in,
                              void* d_out, int out_size, void* d_ws, size_t ws_size,
                              hipStream_t stream) {
    const float* x   = (const float*)d_in[0];
    const int*   ei  = (const int*)  d_in[1];   // [2, E]
    const float* W1  = (const float*)d_in[2];
    const float* b1  = (const float*)d_in[3];
    const float* W2  = (const float*)d_in[4];
    const float* b2  = (const float*)d_in[5];
    const float* W3  = (const float*)d_in[6];
    const float* b3  = (const float*)d_in[7];
    float* out = (float*)d_out;

    const int N = N_NODES, E = N_EDGES;
    const int* row = ei;
    const int* col = ei + E;

    // ---- workspace layout (bytes, 256-aligned chunks) ----
    size_t off = 0;
    auto alloc = [&](size_t bytes) { size_t o = off; off += (bytes + 255) & ~(size_t)255; return o; };
    size_t o_dinv   = alloc((size_t)N * 4);
    size_t o_ptr    = alloc((size_t)(N + 1) * 4);
    size_t o_cursor = alloc((size_t)N * 4);        // also deg-count buffer
    size_t o_rowsrt = alloc((size_t)E * 4);
    size_t o_nrmsrt = alloc((size_t)E * 4);
    size_t o_G      = alloc((size_t)N * 2 * 4);
    size_t o_B1     = alloc((size_t)N * HIDDEN * 2);   // bf16: Xa then Ha
    size_t o_B2     = alloc((size_t)N * HIDDEN * 2);   // bf16: H1 then H2
    if (ws_size < off) return;   // still too small -> visible zero-output failure

    char* ws = (char*)d_ws;
    float*    dinv    = (float*)(ws + o_dinv);
    int*      ptr     = (int*)  (ws + o_ptr);
    int*      cursor  = (int*)  (ws + o_cursor);
    int*      row_srt = (int*)  (ws + o_rowsrt);
    float*    nrm_srt = (float*)(ws + o_nrmsrt);
    float*    G       = (float*)(ws + o_G);
    ushort_t* B1      = (ushort_t*)(ws + o_B1);
    ushort_t* B2      = (ushort_t*)(ws + o_B2);

    const int B = 256;

    // 1. CSR build + dinv
    hipMemsetAsync(cursor, 0, (size_t)N * 4, stream);
    count_kernel<<<(E + B - 1) / B, B, 0, stream>>>(col, cursor, E);
    dinv_kernel<<<(N + B - 1) / B, B, 0, stream>>>(cursor, dinv, N);
    scan_kernel<<<1, SCAN_T, 0, stream>>>(cursor, ptr, N);
    scatter_kernel<<<(E + B - 1) / B, B, 0, stream>>>(row, col, dinv, cursor, row_srt, nrm_srt, E);

    // 2. Xa = A @ x -> B1 (bf16, N x 165)
    agg165_kernel<<<(N * 64 + B - 1) / B, B, 0, stream>>>(x, dinv, ptr, row_srt, nrm_srt, B1, N);

    // 3. H1 = relu(Xa @ W1 + b1) -> B2
    {
        dim3 grid(N / TM, HIDDEN / TN);
        gemm_bias_kernel<true><<<grid, 256, 0, stream>>>(B1, W1, b1, B2, N, HIDDEN, F_IN);
    }

    // 4. Ha = A @ H1 -> B1
    agg384_kernel<<<(N * 64 + B - 1) / B, B, 0, stream>>>(B2, dinv, ptr, row_srt, nrm_srt, B1, N);

    // 5. H2 = relu(Ha @ W2 + b2) -> B2
    {
        dim3 grid(N / TM, HIDDEN / TN);
        gemm_bias_kernel<true><<<grid, 256, 0, stream>>>(B1, W2, b2, B2, N, HIDDEN, HIDDEN);
    }

    // 6. G = H2 @ W3 (N x 2, fp32)
    gemm_n2_kernel<<<(N * 64 + B - 1) / B, B, 0, stream>>>(B2, W3, G, N);

    // 7. out = A @ G + b3
    out_kernel<<<(N + B - 1) / B, B, 0, stream>>>(G, dinv, ptr, row_srt, nrm_srt, b3, out, N);
}

// Round 4
// 1002.035 us; speedup vs baseline: 2.1393x; 2.1393x over previous
//
#include <hip/hip_runtime.h>
#include <hip/hip_bf16.h>

#define N_NODES 200000
#define N_EDGES 500000
#define F_IN    165
#define HIDDEN  384
#define F_OUT   2

#define KPAD1   192          // F_IN padded to multiple of 32
#define M_TILES 1563         // ceil(200000/128)
#define M_PAD   (M_TILES * 128)

typedef unsigned short ushort_t;
typedef unsigned int   uint_t;

using bf16x8 = __attribute__((ext_vector_type(8))) short;
using f32x4  = __attribute__((ext_vector_type(4))) float;

__device__ __forceinline__ float bf2f(uint_t u) {
    return __uint_as_float(u << 16);
}
__device__ __forceinline__ ushort_t f2bf(float x) {
    uint_t b = __float_as_uint(x);
    return (ushort_t)((b + 0x7FFFu + ((b >> 16) & 1u)) >> 16);  // RNE
}

// ---------------------------------------------------------------------------
// degree count (in-degree via col), int atomics into `cnt`
// ---------------------------------------------------------------------------
__global__ void count_kernel(const int* __restrict__ col, int* __restrict__ cnt, int E) {
    int e = blockIdx.x * blockDim.x + threadIdx.x;
    if (e < E) atomicAdd(&cnt[col[e]], 1);
}

__global__ void dinv_kernel(const int* __restrict__ cnt, float* __restrict__ dinv, int n) {
    int i = blockIdx.x * blockDim.x + threadIdx.x;
    if (i < n) dinv[i] = rsqrtf((float)(cnt[i] + 1));   // +1 self loop
}

// ---------------------------------------------------------------------------
// single-block exclusive scan
// ---------------------------------------------------------------------------
#define SCAN_T 1024
__global__ __launch_bounds__(SCAN_T) void scan_kernel(int* __restrict__ cnt_cursor,
                                                      int* __restrict__ ptr, int N) {
    __shared__ int sh[SCAN_T];
    int t = threadIdx.x;
    int chunk = (N + SCAN_T - 1) / SCAN_T;
    int s = t * chunk;
    int epos = min(s + chunk, N);
    int sum = 0;
    for (int j = s; j < epos; ++j) sum += cnt_cursor[j];
    sh[t] = sum;
    __syncthreads();
    for (int off = 1; off < SCAN_T; off <<= 1) {
        int v = (t >= off) ? sh[t - off] : 0;
        __syncthreads();
        sh[t] += v;
        __syncthreads();
    }
    int run = (t == 0) ? 0 : sh[t - 1];
    for (int j = s; j < epos; ++j) {
        int c = cnt_cursor[j];
        ptr[j] = run;
        cnt_cursor[j] = run;
        run += c;
    }
    if (epos == N) ptr[N] = run;
}

// ---------------------------------------------------------------------------
// scatter edges into CSR-by-col order; nrm = dinv[r]*dinv[c]
// ---------------------------------------------------------------------------
__global__ void scatter_kernel(const int* __restrict__ row, const int* __restrict__ col,
                               const float* __restrict__ dinv,
                               int* __restrict__ cursor,
                               int* __restrict__ row_srt, float* __restrict__ nrm_srt, int E) {
    int e = blockIdx.x * blockDim.x + threadIdx.x;
    if (e >= E) return;
    int r = row[e], c = col[e];
    int pos = atomicAdd(&cursor[c], 1);
    row_srt[pos] = r;
    nrm_srt[pos] = dinv[r] * dinv[c];
}

// ---------------------------------------------------------------------------
// agg for x (fp32 in, F=165) -> bf16 out, row stride KPAD1. one wave per node.
// pad cols [165,192) left untouched (Wt1 pad rows are zero, so don't care).
// ---------------------------------------------------------------------------
__global__ __launch_bounds__(256) void agg165_kernel(
        const float* __restrict__ X, const float* __restrict__ dinv,
        const int* __restrict__ ptr, const int* __restrict__ row_srt,
        const float* __restrict__ nrm_srt, ushort_t* __restrict__ out, int N) {
    int w    = (blockIdx.x * blockDim.x + threadIdx.x) >> 6;
    int lane = threadIdx.x & 63;
    if (w >= N) return;
    float d2 = dinv[w]; d2 *= d2;
    int f0 = lane, f1 = lane + 64, f2 = lane + 128;
    const float* xs = X + (size_t)w * F_IN;
    float a0 = xs[f0] * d2;
    float a1 = xs[f1] * d2;
    float a2 = (f2 < F_IN) ? xs[f2] * d2 : 0.0f;
    int e0 = ptr[w], e1 = ptr[w + 1];
    for (int e = e0; e < e1; ++e) {
        int r = row_srt[e];
        float wg = nrm_srt[e];
        const float* xr = X + (size_t)r * F_IN;
        a0 = fmaf(xr[f0], wg, a0);
        a1 = fmaf(xr[f1], wg, a1);
        if (f2 < F_IN) a2 = fmaf(xr[f2], wg, a2);
    }
    ushort_t* o = out + (size_t)w * KPAD1;
    o[f0] = f2bf(a0);
    o[f1] = f2bf(a1);
    if (f2 < F_IN) o[f2] = f2bf(a2);
}

// ---------------------------------------------------------------------------
// agg for bf16 H (F=384, stride 384) -> bf16 out (stride 384)
// ---------------------------------------------------------------------------
__global__ __launch_bounds__(256) void agg384_kernel(
        const ushort_t* __restrict__ H, const float* __restrict__ dinv,
        const int* __restrict__ ptr, const int* __restrict__ row_srt,
        const float* __restrict__ nrm_srt, ushort_t* __restrict__ out, int N) {
    int w    = (blockIdx.x * blockDim.x + threadIdx.x) >> 6;
    int lane = threadIdx.x & 63;
    if (w >= N) return;
    float d2 = dinv[w]; d2 *= d2;
    const uint_t* self = (const uint_t*)(H + (size_t)w * HIDDEN);
    float ax[3], ay[3];
    #pragma unroll
    for (int j = 0; j < 3; ++j) {
        uint_t u = self[lane + 64 * j];
        ax[j] = bf2f(u & 0xFFFFu) * d2;
        ay[j] = bf2f(u >> 16) * d2;
    }
    int e0 = ptr[w], e1 = ptr[w + 1];
    for (int e = e0; e < e1; ++e) {
        int r = row_srt[e];
        float wg = nrm_srt[e];
        const uint_t* hr = (const uint_t*)(H + (size_t)r * HIDDEN);
        #pragma unroll
        for (int j = 0; j < 3; ++j) {
            uint_t u = hr[lane + 64 * j];
            ax[j] = fmaf(bf2f(u & 0xFFFFu), wg, ax[j]);
            ay[j] = fmaf(bf2f(u >> 16), wg, ay[j]);
        }
    }
    uint_t* o = (uint_t*)(out + (size_t)w * HIDDEN);
    #pragma unroll
    for (int j = 0; j < 3; ++j)
        o[lane + 64 * j] = (uint_t)f2bf(ax[j]) | ((uint_t)f2bf(ay[j]) << 16);
}

// ---------------------------------------------------------------------------
// weight prep: Wt[n][k] = bf16(W[k][n]), zero pad for k >= Kin
// ---------------------------------------------------------------------------
__global__ void prep_wt_kernel(const float* __restrict__ W, ushort_t* __restrict__ Wt,
                               int Kin, int Kpad, int Nn) {
    int idx = blockIdx.x * blockDim.x + threadIdx.x;
    if (idx >= Nn * Kpad) return;
    int n = idx / Kpad, k = idx - n * Kpad;
    float v = (k < Kin) ? W[(size_t)k * Nn + n] : 0.0f;
    Wt[idx] = f2bf(v);
}

// ---------------------------------------------------------------------------
// MFMA bf16 GEMM: C[M_PAD][Nn](bf16) = relu(A[M_PAD][Ks](bf16) @ Wt[Nn][Ks]^T + bias)
// block tile 128x128, BK=32, 4 waves (2x2), wave tile 64x64 = 4x4 frags of 16x16x32
// LDS: linear [rows][32] bf16 with 16B-chunk XOR swizzle (chunk ^= (row>>1)&3)
// B rows permuted in LDS: slot ni*16+p holds output col ni+4p -> lane owns 4
// consecutive output cols -> ushort4 epilogue stores.
// ---------------------------------------------------------------------------
#define GBK 32

template<bool RELU>
__global__ __launch_bounds__(256) void mfma_gemm_kernel(
        const ushort_t* __restrict__ A, const ushort_t* __restrict__ Wt,
        const float* __restrict__ bias, ushort_t* __restrict__ C,
        int Ks, int Nn) {
    __shared__ ushort_t As[128 * GBK];
    __shared__ ushort_t Bs[128 * GBK];

    const int tid  = threadIdx.x;
    const int lane = tid & 63;
    const int w    = tid >> 6;
    const int wm   = w & 1;
    const int wn   = w >> 1;
    const int bn   = blockIdx.x * 128;
    const int bm   = blockIdx.y * 128;

    // ---- staging: each thread stages rows rA and rA+64, 16B chunk q ----
    const int rA = tid >> 2;       // 0..63
    const int q  = tid & 3;        // 16B chunk (8 bf16) within 64B row

    auto lds_off = [](int row, int chunk) {
        return row * GBK + ((chunk ^ ((row >> 1) & 3)) * 8);   // ushort units
    };
    const int wOff0 = lds_off(rA, q);
    const int wOff1 = lds_off(rA + 64, q);

    // B-row permutation: LDS slot s (per 64-group): s = ni*16+p holds col ni+4p
    auto brow = [](int s) {
        return ((s >> 6) * 64) + ((s & 63) >> 4) + ((s & 15) * 4);
    };
    const int gB0 = brow(rA);
    const int gB1 = brow(rA + 64);

    const ushort_t* Ag0 = A  + (size_t)(bm + rA) * Ks + q * 8;
    const ushort_t* Ag1 = Ag0 + (size_t)64 * Ks;
    const ushort_t* Bg0 = Wt + (size_t)(bn + gB0) * Ks + q * 8;
    const ushort_t* Bg1 = Wt + (size_t)(bn + gB1) * Ks + q * 8;

    // ---- fragment read offsets ----
    const int p     = lane & 15;
    const int khalf = lane >> 4;
    const int qf    = khalf ^ ((p >> 1) & 3);   // (row>>1)&3 == (p>>1)&3 (bases mult of 16)
    int aoff[4], boff[4];
    #pragma unroll
    for (int f = 0; f < 4; ++f) {
        aoff[f] = (wm * 64 + f * 16 + p) * GBK + qf * 8;
        boff[f] = (wn * 64 + f * 16 + p) * GBK + qf * 8;
    }

    f32x4 acc[4][4] = {};

    const int ksteps = Ks >> 5;
    for (int kt = 0; kt < ksteps; ++kt) {
        const int k0 = kt * GBK;
        uint4 va0 = *reinterpret_cast<const uint4*>(Ag0 + k0);
        uint4 va1 = *reinterpret_cast<const uint4*>(Ag1 + k0);
        uint4 vb0 = *reinterpret_cast<const uint4*>(Bg0 + k0);
        uint4 vb1 = *reinterpret_cast<const uint4*>(Bg1 + k0);
        *reinterpret_cast<uint4*>(&As[wOff0]) = va0;
        *reinterpret_cast<uint4*>(&As[wOff1]) = va1;
        *reinterpret_cast<uint4*>(&Bs[wOff0]) = vb0;
        *reinterpret_cast<uint4*>(&Bs[wOff1]) = vb1;
        __syncthreads();

        bf16x8 af[4], bfr[4];
        #pragma unroll
        for (int f = 0; f < 4; ++f) {
            af[f]  = *reinterpret_cast<const bf16x8*>(&As[aoff[f]]);
            bfr[f] = *reinterpret_cast<const bf16x8*>(&Bs[boff[f]]);
        }
        #pragma unroll
        for (int mi = 0; mi < 4; ++mi)
            #pragma unroll
            for (int ni = 0; ni < 4; ++ni)
                acc[mi][ni] = __builtin_amdgcn_mfma_f32_16x16x32_bf16(
                    af[mi], bfr[ni], acc[mi][ni], 0, 0, 0);
        __syncthreads();
    }

    // ---- epilogue: lane owns output cols colbase..colbase+3 ----
    const int colbase = bn + wn * 64 + p * 4;
    const float4 bb = *reinterpret_cast<const float4*>(bias + colbase);
    const float bias4[4] = {bb.x, bb.y, bb.z, bb.w};
    #pragma unroll
    for (int mi = 0; mi < 4; ++mi) {
        const int rowbase = bm + wm * 64 + mi * 16 + khalf * 4;
        #pragma unroll
        for (int j = 0; j < 4; ++j) {
            float v0 = acc[mi][0][j] + bias4[0];
            float v1 = acc[mi][1][j] + bias4[1];
            float v2 = acc[mi][2][j] + bias4[2];
            float v3 = acc[mi][3][j] + bias4[3];
            if (RELU) {
                v0 = fmaxf(v0, 0.f); v1 = fmaxf(v1, 0.f);
                v2 = fmaxf(v2, 0.f); v3 = fmaxf(v3, 0.f);
            }
            ushort4 o;
            o.x = f2bf(v0); o.y = f2bf(v1); o.z = f2bf(v2); o.w = f2bf(v3);
            *reinterpret_cast<ushort4*>(C + (size_t)(rowbase + j) * Nn + colbase) = o;
        }
    }
}

// ---------------------------------------------------------------------------
// G[M,2] = A[M,384](bf16) @ W[384,2](f32) ; wave per row
// ---------------------------------------------------------------------------
__global__ __launch_bounds__(256) void gemm_n2_kernel(
        const ushort_t* __restrict__ A, const float* __restrict__ W,
        float* __restrict__ G, int M) {
    int w    = (blockIdx.x * blockDim.x + threadIdx.x) >> 6;
    int lane = threadIdx.x & 63;
    if (w >= M) return;
    const uint_t* a = (const uint_t*)(A + (size_t)w * HIDDEN);
    float s0 = 0.f, s1 = 0.f;
    #pragma unroll
    for (int j = 0; j < 3; ++j) {
        int f2 = lane + 64 * j;
        uint_t u = a[f2];
        float alo = bf2f(u & 0xFFFFu), ahi = bf2f(u >> 16);
        int k = f2 * 2;
        s0 = fmaf(alo, W[k * 2 + 0], s0);
        s1 = fmaf(alo, W[k * 2 + 1], s1);
        s0 = fmaf(ahi, W[k * 2 + 2], s0);
        s1 = fmaf(ahi, W[k * 2 + 3], s1);
    }
    #pragma unroll
    for (int off = 32; off; off >>= 1) {
        s0 += __shfl_down(s0, off);
        s1 += __shfl_down(s1, off);
    }
    if (lane == 0) { G[(size_t)w * 2] = s0; G[(size_t)w * 2 + 1] = s1; }
}

// ---------------------------------------------------------------------------
// final: out[i,:] = dinv[i]^2*G[i,:] + sum_e nrm_e*G[row_e,:] + b3
// ---------------------------------------------------------------------------
__global__ void out_kernel(const float* __restrict__ G, const float* __restrict__ dinv,
                           const int* __restrict__ ptr, const int* __restrict__ row_srt,
                           const float* __restrict__ nrm_srt, const float* __restrict__ b3,
                           float* __restrict__ out, int N) {
    int i = blockIdx.x * blockDim.x + threadIdx.x;
    if (i >= N) return;
    float d2 = dinv[i]; d2 *= d2;
    float a0 = G[(size_t)i * 2 + 0] * d2 + b3[0];
    float a1 = G[(size_t)i * 2 + 1] * d2 + b3[1];
    int e0 = ptr[i], e1 = ptr[i + 1];
    for (int e = e0; e < e1; ++e) {
        int r = row_srt[e];
        float wg = nrm_srt[e];
        a0 = fmaf(G[(size_t)r * 2 + 0], wg, a0);
        a1 = fmaf(G[(size_t)r * 2 + 1], wg, a1);
    }
    out[(size_t)i * 2 + 0] = a0;
    out[(size_t)i * 2 + 1] = a1;
}

// ---------------------------------------------------------------------------
extern "C" void kernel_launch(void* const* d_in, const int* in_sizes, int n_in,
                              void* d_out, int out_size, void* d_ws, size_t ws_size,
                              hipStream_t stream) {
    const float* x   = (const float*)d_in[0];
    const int*   ei  = (const int*)  d_in[1];   // [2, E]
    const float* W1  = (const float*)d_in[2];
    const float* b1  = (const float*)d_in[3];
    const float* W2  = (const float*)d_in[4];
    const float* b2  = (const float*)d_in[5];
    const float* W3  = (const float*)d_in[6];
    const float* b3  = (const float*)d_in[7];
    float* out = (float*)d_out;

    const int N = N_NODES, E = N_EDGES;
    const int* row = ei;
    const int* col = ei + E;

    // ---- workspace layout (bytes, 256-aligned chunks) ----
    size_t off = 0;
    auto alloc = [&](size_t bytes) { size_t o = off; off += (bytes + 255) & ~(size_t)255; return o; };
    size_t o_dinv   = alloc((size_t)N * 4);
    size_t o_ptr    = alloc((size_t)(N + 1) * 4);
    size_t o_cursor = alloc((size_t)N * 4);
    size_t o_rowsrt = alloc((size_t)E * 4);
    size_t o_nrmsrt = alloc((size_t)E * 4);
    size_t o_G      = alloc((size_t)N * 2 * 4);
    size_t o_Wt1    = alloc((size_t)HIDDEN * KPAD1 * 2);
    size_t o_Wt2    = alloc((size_t)HIDDEN * HIDDEN * 2);
    size_t o_B1     = alloc((size_t)M_PAD * HIDDEN * 2);   // bf16: Xa(stride 192) then Ha(384)
    size_t o_B2     = alloc((size_t)M_PAD * HIDDEN * 2);   // bf16: H1 then H2
    if (ws_size < off) return;   // visible zero-output failure if too small

    char* ws = (char*)d_ws;
    float*    dinv    = (float*)(ws + o_dinv);
    int*      ptr     = (int*)  (ws + o_ptr);
    int*      cursor  = (int*)  (ws + o_cursor);
    int*      row_srt = (int*)  (ws + o_rowsrt);
    float*    nrm_srt = (float*)(ws + o_nrmsrt);
    float*    G       = (float*)(ws + o_G);
    ushort_t* Wt1     = (ushort_t*)(ws + o_Wt1);
    ushort_t* Wt2     = (ushort_t*)(ws + o_Wt2);
    ushort_t* B1      = (ushort_t*)(ws + o_B1);
    ushort_t* B2      = (ushort_t*)(ws + o_B2);

    const int B = 256;

    // 0. weight prep (bf16 transpose, zero-padded K)
    prep_wt_kernel<<<(HIDDEN * KPAD1 + B - 1) / B, B, 0, stream>>>(W1, Wt1, F_IN, KPAD1, HIDDEN);
    prep_wt_kernel<<<(HIDDEN * HIDDEN + B - 1) / B, B, 0, stream>>>(W2, Wt2, HIDDEN, HIDDEN, HIDDEN);

    // 1. CSR build + dinv
    hipMemsetAsync(cursor, 0, (size_t)N * 4, stream);
    count_kernel<<<(E + B - 1) / B, B, 0, stream>>>(col, cursor, E);
    dinv_kernel<<<(N + B - 1) / B, B, 0, stream>>>(cursor, dinv, N);
    scan_kernel<<<1, SCAN_T, 0, stream>>>(cursor, ptr, N);
    scatter_kernel<<<(E + B - 1) / B, B, 0, stream>>>(row, col, dinv, cursor, row_srt, nrm_srt, E);

    // 2. Xa = A @ x -> B1 (bf16, stride KPAD1)
    agg165_kernel<<<(N * 64 + B - 1) / B, B, 0, stream>>>(x, dinv, ptr, row_srt, nrm_srt, B1, N);

    // 3. H1 = relu(Xa @ W1 + b1) -> B2
    {
        dim3 grid(HIDDEN / 128, M_TILES);   // col-group fastest -> A row-panel L2 reuse
        mfma_gemm_kernel<true><<<grid, 256, 0, stream>>>(B1, Wt1, b1, B2, KPAD1, HIDDEN);
    }

    // 4. Ha = A @ H1 -> B1 (stride 384)
    agg384_kernel<<<(N * 64 + B - 1) / B, B, 0, stream>>>(B2, dinv, ptr, row_srt, nrm_srt, B1, N);

    // 5. H2 = relu(Ha @ W2 + b2) -> B2
    {
        dim3 grid(HIDDEN / 128, M_TILES);
        mfma_gemm_kernel<true><<<grid, 256, 0, stream>>>(B1, Wt2, b2, B2, HIDDEN, HIDDEN);
    }

    // 6. G = H2 @ W3 (N x 2, fp32)
    gemm_n2_kernel<<<(N * 64 + B - 1) / B, B, 0, stream>>>(B2, W3, G, N);

    // 7. out = A @ G + b3
    out_kernel<<<(N + B - 1) / B, B, 0, stream>>>(G, dinv, ptr, row_srt, nrm_srt, b3, out, N);
}

// Round 7
// 557.115 us; speedup vs baseline: 3.8477x; 1.7986x over previous
//
#include <hip/hip_runtime.h>
#include <hip/hip_bf16.h>

#define N_NODES 200000
#define N_EDGES 500000
#define F_IN    165
#define HIDDEN  384
#define F_OUT   2

#define KPAD1   192          // F_IN padded to multiple of 32
#define M_TILES 1563         // ceil(200000/128)
#define M_PAD   (M_TILES * 128)
#define NB_SCAN 782          // ceil(200000/256)

typedef unsigned short ushort_t;
typedef unsigned int   uint_t;

using bf16x8 = __attribute__((ext_vector_type(8))) short;
using f32x4  = __attribute__((ext_vector_type(4))) float;

__device__ __forceinline__ float bf2f(uint_t u) {
    return __uint_as_float(u << 16);
}
__device__ __forceinline__ ushort_t f2bf(float x) {
    uint_t b = __float_as_uint(x);
    return (ushort_t)((b + 0x7FFFu + ((b >> 16) & 1u)) >> 16);  // RNE
}

// ---------------------------------------------------------------------------
// degree count (in-degree via col), int atomics into `cnt`
// ---------------------------------------------------------------------------
__global__ void count_kernel(const int* __restrict__ col, int* __restrict__ cnt, int E) {
    int e = blockIdx.x * blockDim.x + threadIdx.x;
    if (e < E) atomicAdd(&cnt[col[e]], 1);
}

__global__ void dinv_kernel(const int* __restrict__ cnt, float* __restrict__ dinv, int n) {
    int i = blockIdx.x * blockDim.x + threadIdx.x;
    if (i < n) dinv[i] = rsqrtf((float)(cnt[i] + 1));   // +1 self loop
}

// ---------------------------------------------------------------------------
// two-level exclusive scan of cnt[0..N) -> ptr (local prefix), bsum (block sums)
// ---------------------------------------------------------------------------
__global__ __launch_bounds__(256) void scan1_kernel(const int* __restrict__ cnt,
                                                    int* __restrict__ loc,
                                                    int* __restrict__ bsum, int N) {
    __shared__ int sh[256];
    int t = threadIdx.x;
    int i = blockIdx.x * 256 + t;
    int v = (i < N) ? cnt[i] : 0;
    sh[t] = v;
    __syncthreads();
    #pragma unroll
    for (int off = 1; off < 256; off <<= 1) {
        int u = (t >= off) ? sh[t - off] : 0;
        __syncthreads();
        sh[t] += u;
        __syncthreads();
    }
    int incl = sh[t];
    if (i < N) loc[i] = incl - v;            // exclusive local prefix
    if (t == 255) bsum[blockIdx.x] = incl;   // block total
}

__global__ __launch_bounds__(1024) void scan2_kernel(int* __restrict__ bsum, int NB) {
    __shared__ int sh[1024];
    int t = threadIdx.x;
    int v = (t < NB) ? bsum[t] : 0;
    sh[t] = v;
    __syncthreads();
    #pragma unroll
    for (int off = 1; off < 1024; off <<= 1) {
        int u = (t >= off) ? sh[t - off] : 0;
        __syncthreads();
        sh[t] += u;
        __syncthreads();
    }
    if (t < NB) bsum[t] = sh[t] - v;         // exclusive
}

__global__ __launch_bounds__(256) void scan3_kernel(int* __restrict__ ptr,
                                                    int* __restrict__ cursor,
                                                    const int* __restrict__ bsum,
                                                    int N, int E) {
    int t = threadIdx.x;
    int i = blockIdx.x * 256 + t;
    if (i < N) {
        int p = ptr[i] + bsum[blockIdx.x];
        ptr[i] = p;
        cursor[i] = p;
    }
    if (i == 0) ptr[N] = E;
}

// ---------------------------------------------------------------------------
// scatter edges into CSR-by-col order; nrm = dinv[r]*dinv[c]
// ---------------------------------------------------------------------------
__global__ void scatter_kernel(const int* __restrict__ row, const int* __restrict__ col,
                               const float* __restrict__ dinv,
                               int* __restrict__ cursor,
                               int* __restrict__ row_srt, float* __restrict__ nrm_srt, int E) {
    int e = blockIdx.x * blockDim.x + threadIdx.x;
    if (e >= E) return;
    int r = row[e], c = col[e];
    int pos = atomicAdd(&cursor[c], 1);
    row_srt[pos] = r;
    nrm_srt[pos] = dinv[r] * dinv[c];
}

// ---------------------------------------------------------------------------
// agg for x (fp32 in, F=165) -> bf16 out, row stride KPAD1. one wave per node.
// ---------------------------------------------------------------------------
__global__ __launch_bounds__(256) void agg165_kernel(
        const float* __restrict__ X, const float* __restrict__ dinv,
        const int* __restrict__ ptr, const int* __restrict__ row_srt,
        const float* __restrict__ nrm_srt, ushort_t* __restrict__ out, int N) {
    int w    = (blockIdx.x * blockDim.x + threadIdx.x) >> 6;
    int lane = threadIdx.x & 63;
    if (w >= N) return;
    float d2 = dinv[w]; d2 *= d2;
    int f0 = lane, f1 = lane + 64, f2 = lane + 128;
    const float* xs = X + (size_t)w * F_IN;
    float a0 = xs[f0] * d2;
    float a1 = xs[f1] * d2;
    float a2 = (f2 < F_IN) ? xs[f2] * d2 : 0.0f;
    int e0 = ptr[w], e1 = ptr[w + 1];
    for (int e = e0; e < e1; ++e) {
        int r = row_srt[e];
        float wg = nrm_srt[e];
        const float* xr = X + (size_t)r * F_IN;
        a0 = fmaf(xr[f0], wg, a0);
        a1 = fmaf(xr[f1], wg, a1);
        if (f2 < F_IN) a2 = fmaf(xr[f2], wg, a2);
    }
    ushort_t* o = out + (size_t)w * KPAD1;
    o[f0] = f2bf(a0);
    o[f1] = f2bf(a1);
    if (f2 < F_IN) o[f2] = f2bf(a2);
}

// ---------------------------------------------------------------------------
// agg for bf16 H (F=384, stride 384) -> bf16 out (stride 384)
// ---------------------------------------------------------------------------
__global__ __launch_bounds__(256) void agg384_kernel(
        const ushort_t* __restrict__ H, const float* __restrict__ dinv,
        const int* __restrict__ ptr, const int* __restrict__ row_srt,
        const float* __restrict__ nrm_srt, ushort_t* __restrict__ out, int N) {
    int w    = (blockIdx.x * blockDim.x + threadIdx.x) >> 6;
    int lane = threadIdx.x & 63;
    if (w >= N) return;
    float d2 = dinv[w]; d2 *= d2;
    const uint_t* self = (const uint_t*)(H + (size_t)w * HIDDEN);
    float ax[3], ay[3];
    #pragma unroll
    for (int j = 0; j < 3; ++j) {
        uint_t u = self[lane + 64 * j];
        ax[j] = bf2f(u & 0xFFFFu) * d2;
        ay[j] = bf2f(u >> 16) * d2;
    }
    int e0 = ptr[w], e1 = ptr[w + 1];
    for (int e = e0; e < e1; ++e) {
        int r = row_srt[e];
        float wg = nrm_srt[e];
        const uint_t* hr = (const uint_t*)(H + (size_t)r * HIDDEN);
        #pragma unroll
        for (int j = 0; j < 3; ++j) {
            uint_t u = hr[lane + 64 * j];
            ax[j] = fmaf(bf2f(u & 0xFFFFu), wg, ax[j]);
            ay[j] = fmaf(bf2f(u >> 16), wg, ay[j]);
        }
    }
    uint_t* o = (uint_t*)(out + (size_t)w * HIDDEN);
    #pragma unroll
    for (int j = 0; j < 3; ++j)
        o[lane + 64 * j] = (uint_t)f2bf(ax[j]) | ((uint_t)f2bf(ay[j]) << 16);
}

// ---------------------------------------------------------------------------
// weight prep: Wt[n][k] = bf16(W[k][n]), zero pad for k >= Kin
// ---------------------------------------------------------------------------
__global__ void prep_wt_kernel(const float* __restrict__ W, ushort_t* __restrict__ Wt,
                               int Kin, int Kpad, int Nn) {
    int idx = blockIdx.x * blockDim.x + threadIdx.x;
    if (idx >= Nn * Kpad) return;
    int n = idx / Kpad, k = idx - n * Kpad;
    float v = (k < Kin) ? W[(size_t)k * Nn + n] : 0.0f;
    Wt[idx] = f2bf(v);
}

// ---------------------------------------------------------------------------
// MFMA bf16 GEMM: C[M_PAD][Nn](bf16) = relu(A[M_PAD][Ks](bf16) @ Wt[Nn][Ks]^T + bias)
// block tile 128x128, BK=32, 4 waves (2x2), wave tile 64x64 = 4x4 frags of 16x16x32
// ---------------------------------------------------------------------------
#define GBK 32

template<bool RELU>
__global__ __launch_bounds__(256) void mfma_gemm_kernel(
        const ushort_t* __restrict__ A, const ushort_t* __restrict__ Wt,
        const float* __restrict__ bias, ushort_t* __restrict__ C,
        int Ks, int Nn) {
    __shared__ ushort_t As[128 * GBK];
    __shared__ ushort_t Bs[128 * GBK];

    const int tid  = threadIdx.x;
    const int lane = tid & 63;
    const int w    = tid >> 6;
    const int wm   = w & 1;
    const int wn   = w >> 1;
    const int bn   = blockIdx.x * 128;
    const int bm   = blockIdx.y * 128;

    const int rA = tid >> 2;       // 0..63
    const int q  = tid & 3;        // 16B chunk (8 bf16) within 64B row

    auto lds_off = [](int row, int chunk) {
        return row * GBK + ((chunk ^ ((row >> 1) & 3)) * 8);   // ushort units
    };
    const int wOff0 = lds_off(rA, q);
    const int wOff1 = lds_off(rA + 64, q);

    auto brow = [](int s) {
        return ((s >> 6) * 64) + ((s & 63) >> 4) + ((s & 15) * 4);
    };
    const int gB0 = brow(rA);
    const int gB1 = brow(rA + 64);

    const ushort_t* Ag0 = A  + (size_t)(bm + rA) * Ks + q * 8;
    const ushort_t* Ag1 = Ag0 + (size_t)64 * Ks;
    const ushort_t* Bg0 = Wt + (size_t)(bn + gB0) * Ks + q * 8;
    const ushort_t* Bg1 = Wt + (size_t)(bn + gB1) * Ks + q * 8;

    const int p     = lane & 15;
    const int khalf = lane >> 4;
    const int qf    = khalf ^ ((p >> 1) & 3);
    int aoff[4], boff[4];
    #pragma unroll
    for (int f = 0; f < 4; ++f) {
        aoff[f] = (wm * 64 + f * 16 + p) * GBK + qf * 8;
        boff[f] = (wn * 64 + f * 16 + p) * GBK + qf * 8;
    }

    f32x4 acc[4][4] = {};

    const int ksteps = Ks >> 5;
    for (int kt = 0; kt < ksteps; ++kt) {
        const int k0 = kt * GBK;
        uint4 va0 = *reinterpret_cast<const uint4*>(Ag0 + k0);
        uint4 va1 = *reinterpret_cast<const uint4*>(Ag1 + k0);
        uint4 vb0 = *reinterpret_cast<const uint4*>(Bg0 + k0);
        uint4 vb1 = *reinterpret_cast<const uint4*>(Bg1 + k0);
        *reinterpret_cast<uint4*>(&As[wOff0]) = va0;
        *reinterpret_cast<uint4*>(&As[wOff1]) = va1;
        *reinterpret_cast<uint4*>(&Bs[wOff0]) = vb0;
        *reinterpret_cast<uint4*>(&Bs[wOff1]) = vb1;
        __syncthreads();

        bf16x8 af[4], bfr[4];
        #pragma unroll
        for (int f = 0; f < 4; ++f) {
            af[f]  = *reinterpret_cast<const bf16x8*>(&As[aoff[f]]);
            bfr[f] = *reinterpret_cast<const bf16x8*>(&Bs[boff[f]]);
        }
        #pragma unroll
        for (int mi = 0; mi < 4; ++mi)
            #pragma unroll
            for (int ni = 0; ni < 4; ++ni)
                acc[mi][ni] = __builtin_amdgcn_mfma_f32_16x16x32_bf16(
                    af[mi], bfr[ni], acc[mi][ni], 0, 0, 0);
        __syncthreads();
    }

    const int colbase = bn + wn * 64 + p * 4;
    const float4 bb = *reinterpret_cast<const float4*>(bias + colbase);
    const float bias4[4] = {bb.x, bb.y, bb.z, bb.w};
    #pragma unroll
    for (int mi = 0; mi < 4; ++mi) {
        const int rowbase = bm + wm * 64 + mi * 16 + khalf * 4;
        #pragma unroll
        for (int j = 0; j < 4; ++j) {
            float v0 = acc[mi][0][j] + bias4[0];
            float v1 = acc[mi][1][j] + bias4[1];
            float v2 = acc[mi][2][j] + bias4[2];
            float v3 = acc[mi][3][j] + bias4[3];
            if (RELU) {
                v0 = fmaxf(v0, 0.f); v1 = fmaxf(v1, 0.f);
                v2 = fmaxf(v2, 0.f); v3 = fmaxf(v3, 0.f);
            }
            ushort4 o;
            o.x = f2bf(v0); o.y = f2bf(v1); o.z = f2bf(v2); o.w = f2bf(v3);
            *reinterpret_cast<ushort4*>(C + (size_t)(rowbase + j) * Nn + colbase) = o;
        }
    }
}

// ---------------------------------------------------------------------------
// G[M,2] = A[M,384](bf16) @ W[384,2](f32) ; wave per row
// ---------------------------------------------------------------------------
__global__ __launch_bounds__(256) void gemm_n2_kernel(
        const ushort_t* __restrict__ A, const float* __restrict__ W,
        float* __restrict__ G, int M) {
    int w    = (blockIdx.x * blockDim.x + threadIdx.x) >> 6;
    int lane = threadIdx.x & 63;
    if (w >= M) return;
    const uint_t* a = (const uint_t*)(A + (size_t)w * HIDDEN);
    float s0 = 0.f, s1 = 0.f;
    #pragma unroll
    for (int j = 0; j < 3; ++j) {
        int f2 = lane + 64 * j;
        uint_t u = a[f2];
        float alo = bf2f(u & 0xFFFFu), ahi = bf2f(u >> 16);
        int k = f2 * 2;
        s0 = fmaf(alo, W[k * 2 + 0], s0);
        s1 = fmaf(alo, W[k * 2 + 1], s1);
        s0 = fmaf(ahi, W[k * 2 + 2], s0);
        s1 = fmaf(ahi, W[k * 2 + 3], s1);
    }
    #pragma unroll
    for (int off = 32; off; off >>= 1) {
        s0 += __shfl_down(s0, off);
        s1 += __shfl_down(s1, off);
    }
    if (lane == 0) { G[(size_t)w * 2] = s0; G[(size_t)w * 2 + 1] = s1; }
}

// ---------------------------------------------------------------------------
// final: out[i,:] = dinv[i]^2*G[i,:] + sum_e nrm_e*G[row_e,:] + b3
// ---------------------------------------------------------------------------
__global__ void out_kernel(const float* __restrict__ G, const float* __restrict__ dinv,
                           const int* __restrict__ ptr, const int* __restrict__ row_srt,
                           const float* __restrict__ nrm_srt, const float* __restrict__ b3,
                           float* __restrict__ out, int N) {
    int i = blockIdx.x * blockDim.x + threadIdx.x;
    if (i >= N) return;
    float d2 = dinv[i]; d2 *= d2;
    float a0 = G[(size_t)i * 2 + 0] * d2 + b3[0];
    float a1 = G[(size_t)i * 2 + 1] * d2 + b3[1];
    int e0 = ptr[i], e1 = ptr[i + 1];
    for (int e = e0; e < e1; ++e) {
        int r = row_srt[e];
        float wg = nrm_srt[e];
        a0 = fmaf(G[(size_t)r * 2 + 0], wg, a0);
        a1 = fmaf(G[(size_t)r * 2 + 1], wg, a1);
    }
    out[(size_t)i * 2 + 0] = a0;
    out[(size_t)i * 2 + 1] = a1;
}

// ---------------------------------------------------------------------------
extern "C" void kernel_launch(void* const* d_in, const int* in_sizes, int n_in,
                              void* d_out, int out_size, void* d_ws, size_t ws_size,
                              hipStream_t stream) {
    const float* x   = (const float*)d_in[0];
    const int*   ei  = (const int*)  d_in[1];   // [2, E]
    const float* W1  = (const float*)d_in[2];
    const float* b1  = (const float*)d_in[3];
    const float* W2  = (const float*)d_in[4];
    const float* b2  = (const float*)d_in[5];
    const float* W3  = (const float*)d_in[6];
    const float* b3  = (const float*)d_in[7];
    float* out = (float*)d_out;

    const int N = N_NODES, E = N_EDGES;
    const int* row = ei;
    const int* col = ei + E;

    // ---- workspace layout (bytes, 256-aligned chunks) ----
    size_t off = 0;
    auto alloc = [&](size_t bytes) { size_t o = off; off += (bytes + 255) & ~(size_t)255; return o; };
    size_t o_dinv   = alloc((size_t)N * 4);
    size_t o_ptr    = alloc((size_t)(N + 1) * 4);
    size_t o_cnt    = alloc((size_t)N * 4);
    size_t o_cursor = alloc((size_t)N * 4);
    size_t o_bsum   = alloc((size_t)NB_SCAN * 4);
    size_t o_rowsrt = alloc((size_t)E * 4);
    size_t o_nrmsrt = alloc((size_t)E * 4);
    size_t o_G      = alloc((size_t)N * 2 * 4);
    size_t o_Wt1    = alloc((size_t)HIDDEN * KPAD1 * 2);
    size_t o_Wt2    = alloc((size_t)HIDDEN * HIDDEN * 2);
    size_t o_B1     = alloc((size_t)M_PAD * HIDDEN * 2);   // bf16: Xa(stride 192) then Ha(384)
    size_t o_B2     = alloc((size_t)M_PAD * HIDDEN * 2);   // bf16: H1 then H2
    if (ws_size < off) return;   // visible zero-output failure if too small

    char* ws = (char*)d_ws;
    float*    dinv    = (float*)(ws + o_dinv);
    int*      ptr     = (int*)  (ws + o_ptr);
    int*      cnt     = (int*)  (ws + o_cnt);
    int*      cursor  = (int*)  (ws + o_cursor);
    int*      bsum    = (int*)  (ws + o_bsum);
    int*      row_srt = (int*)  (ws + o_rowsrt);
    float*    nrm_srt = (float*)(ws + o_nrmsrt);
    float*    G       = (float*)(ws + o_G);
    ushort_t* Wt1     = (ushort_t*)(ws + o_Wt1);
    ushort_t* Wt2     = (ushort_t*)(ws + o_Wt2);
    ushort_t* B1      = (ushort_t*)(ws + o_B1);
    ushort_t* B2      = (ushort_t*)(ws + o_B2);

    const int B = 256;

    // 0. weight prep (bf16 transpose, zero-padded K)
    prep_wt_kernel<<<(HIDDEN * KPAD1 + B - 1) / B, B, 0, stream>>>(W1, Wt1, F_IN, KPAD1, HIDDEN);
    prep_wt_kernel<<<(HIDDEN * HIDDEN + B - 1) / B, B, 0, stream>>>(W2, Wt2, HIDDEN, HIDDEN, HIDDEN);

    // 1. CSR build + dinv (two-level parallel scan)
    hipMemsetAsync(cnt, 0, (size_t)N * 4, stream);
    count_kernel<<<(E + B - 1) / B, B, 0, stream>>>(col, cnt, E);
    dinv_kernel<<<(N + B - 1) / B, B, 0, stream>>>(cnt, dinv, N);
    scan1_kernel<<<NB_SCAN, 256, 0, stream>>>(cnt, ptr, bsum, N);
    scan2_kernel<<<1, 1024, 0, stream>>>(bsum, NB_SCAN);
    scan3_kernel<<<NB_SCAN, 256, 0, stream>>>(ptr, cursor, bsum, N, E);
    scatter_kernel<<<(E + B - 1) / B, B, 0, stream>>>(row, col, dinv, cursor, row_srt, nrm_srt, E);

    // 2. Xa = A @ x -> B1 (bf16, stride KPAD1)
    agg165_kernel<<<(N * 64 + B - 1) / B, B, 0, stream>>>(x, dinv, ptr, row_srt, nrm_srt, B1, N);

    // 3. H1 = relu(Xa @ W1 + b1) -> B2
    {
        dim3 grid(HIDDEN / 128, M_TILES);
        mfma_gemm_kernel<true><<<grid, 256, 0, stream>>>(B1, Wt1, b1, B2, KPAD1, HIDDEN);
    }

    // 4. Ha = A @ H1 -> B1 (stride 384)
    agg384_kernel<<<(N * 64 + B - 1) / B, B, 0, stream>>>(B2, dinv, ptr, row_srt, nrm_srt, B1, N);

    // 5. H2 = relu(Ha @ W2 + b2) -> B2
    {
        dim3 grid(HIDDEN / 128, M_TILES);
        mfma_gemm_kernel<true><<<grid, 256, 0, stream>>>(B1, Wt2, b2, B2, HIDDEN, HIDDEN);
    }

    // 6. G = H2 @ W3 (N x 2, fp32)
    gemm_n2_kernel<<<(N * 64 + B - 1) / B, B, 0, stream>>>(B2, W3, G, N);

    // 7. out = A @ G + b3
    out_kernel<<<(N + B - 1) / B, B, 0, stream>>>(G, dinv, ptr, row_srt, nrm_srt, b3, out, N);
}

// Round 9
// 539.811 us; speedup vs baseline: 3.9711x; 1.0321x over previous
//
#include <hip/hip_runtime.h>
#include <hip/hip_bf16.h>

#define N_NODES 200000
#define N_EDGES 500000
#define F_IN    165
#define HIDDEN  384
#define F_OUT   2

#define KPAD1   192          // F_IN padded to multiple of 32
#define M_TILES 1563         // ceil(200000/128)
#define M_PAD   (M_TILES * 128)
#define NB_SCAN 782          // ceil(200000/256)

typedef unsigned short ushort_t;
typedef unsigned int   uint_t;

using bf16x8 = __attribute__((ext_vector_type(8))) short;
using f32x4  = __attribute__((ext_vector_type(4))) float;

__device__ __forceinline__ float bf2f(uint_t u) {
    return __uint_as_float(u << 16);
}
__device__ __forceinline__ ushort_t f2bf(float x) {
    uint_t b = __float_as_uint(x);
    return (ushort_t)((b + 0x7FFFu + ((b >> 16) & 1u)) >> 16);  // RNE
}

// ---------------------------------------------------------------------------
// degree count (in-degree via col), int atomics into `cnt`
// ---------------------------------------------------------------------------
__global__ void count_kernel(const int* __restrict__ col, int* __restrict__ cnt, int E) {
    int e = blockIdx.x * blockDim.x + threadIdx.x;
    if (e < E) atomicAdd(&cnt[col[e]], 1);
}

__global__ void dinv_kernel(const int* __restrict__ cnt, float* __restrict__ dinv, int n) {
    int i = blockIdx.x * blockDim.x + threadIdx.x;
    if (i < n) dinv[i] = rsqrtf((float)(cnt[i] + 1));   // +1 self loop
}

// ---------------------------------------------------------------------------
// two-level exclusive scan of cnt[0..N) -> ptr (local prefix), bsum (block sums)
// ---------------------------------------------------------------------------
__global__ __launch_bounds__(256) void scan1_kernel(const int* __restrict__ cnt,
                                                    int* __restrict__ loc,
                                                    int* __restrict__ bsum, int N) {
    __shared__ int sh[256];
    int t = threadIdx.x;
    int i = blockIdx.x * 256 + t;
    int v = (i < N) ? cnt[i] : 0;
    sh[t] = v;
    __syncthreads();
    #pragma unroll
    for (int off = 1; off < 256; off <<= 1) {
        int u = (t >= off) ? sh[t - off] : 0;
        __syncthreads();
        sh[t] += u;
        __syncthreads();
    }
    int incl = sh[t];
    if (i < N) loc[i] = incl - v;            // exclusive local prefix
    if (t == 255) bsum[blockIdx.x] = incl;   // block total
}

__global__ __launch_bounds__(1024) void scan2_kernel(int* __restrict__ bsum, int NB) {
    __shared__ int sh[1024];
    int t = threadIdx.x;
    int v = (t < NB) ? bsum[t] : 0;
    sh[t] = v;
    __syncthreads();
    #pragma unroll
    for (int off = 1; off < 1024; off <<= 1) {
        int u = (t >= off) ? sh[t - off] : 0;
        __syncthreads();
        sh[t] += u;
        __syncthreads();
    }
    if (t < NB) bsum[t] = sh[t] - v;         // exclusive
}

__global__ __launch_bounds__(256) void scan3_kernel(int* __restrict__ ptr,
                                                    int* __restrict__ cursor,
                                                    const int* __restrict__ bsum,
                                                    int N, int E) {
    int t = threadIdx.x;
    int i = blockIdx.x * 256 + t;
    if (i < N) {
        int p = ptr[i] + bsum[blockIdx.x];
        ptr[i] = p;
        cursor[i] = p;
    }
    if (i == 0) ptr[N] = E;
}

// ---------------------------------------------------------------------------
// scatter edges into CSR-by-col order; nrm = dinv[r]*dinv[c]
// ---------------------------------------------------------------------------
__global__ void scatter_kernel(const int* __restrict__ row, const int* __restrict__ col,
                               const float* __restrict__ dinv,
                               int* __restrict__ cursor,
                               int* __restrict__ row_srt, float* __restrict__ nrm_srt, int E) {
    int e = blockIdx.x * blockDim.x + threadIdx.x;
    if (e >= E) return;
    int r = row[e], c = col[e];
    int pos = atomicAdd(&cursor[c], 1);
    row_srt[pos] = r;
    nrm_srt[pos] = dinv[r] * dinv[c];
}

// ---------------------------------------------------------------------------
// convert X fp32 [N][165] -> bf16 [N][192] (zero pad), rows 64B-aligned.
// one thread per output uint (2 bf16).
// ---------------------------------------------------------------------------
__global__ void convx_kernel(const float* __restrict__ X, uint_t* __restrict__ Xb, int total) {
    int idx = blockIdx.x * blockDim.x + threadIdx.x;   // over N*96
    if (idx >= total) return;
    int node = idx / 96, ui = idx - node * 96;
    int f = ui * 2;
    const float* xr = X + (size_t)node * F_IN;
    float lo = (f < F_IN) ? xr[f] : 0.0f;
    float hi = (f + 1 < F_IN) ? xr[f + 1] : 0.0f;
    Xb[idx] = (uint_t)f2bf(lo) | ((uint_t)f2bf(hi) << 16);
}

// ---------------------------------------------------------------------------
// agg for bf16 X (stride 96 uints = 192 ushorts) -> bf16 out, stride KPAD1.
// one wave per node; gathered rows are 6 aligned cache lines (330B live).
// ---------------------------------------------------------------------------
__global__ __launch_bounds__(256) void agg165b_kernel(
        const uint_t* __restrict__ Xb, const float* __restrict__ dinv,
        const int* __restrict__ ptr, const int* __restrict__ row_srt,
        const float* __restrict__ nrm_srt, ushort_t* __restrict__ out, int N) {
    int w    = (blockIdx.x * blockDim.x + threadIdx.x) >> 6;
    int lane = threadIdx.x & 63;
    if (w >= N) return;
    float d2 = dinv[w]; d2 *= d2;
    const uint_t* self = Xb + (size_t)w * 96;
    bool two = (lane < 19);                    // uints 64..82 cover f 128..165
    uint_t u0 = self[lane];
    uint_t u1 = two ? self[64 + lane] : 0u;
    float ax0 = bf2f(u0 & 0xFFFFu) * d2, ay0 = bf2f(u0 >> 16) * d2;
    float ax1 = bf2f(u1 & 0xFFFFu) * d2, ay1 = bf2f(u1 >> 16) * d2;
    int e0 = ptr[w], e1 = ptr[w + 1];
    for (int e = e0; e < e1; ++e) {
        int r = row_srt[e];
        float wg = nrm_srt[e];
        const uint_t* hr = Xb + (size_t)r * 96;
        uint_t v0 = hr[lane];
        uint_t v1 = two ? hr[64 + lane] : 0u;
        ax0 = fmaf(bf2f(v0 & 0xFFFFu), wg, ax0);
        ay0 = fmaf(bf2f(v0 >> 16), wg, ay0);
        ax1 = fmaf(bf2f(v1 & 0xFFFFu), wg, ax1);
        ay1 = fmaf(bf2f(v1 >> 16), wg, ay1);
    }
    uint_t* o = (uint_t*)(out + (size_t)w * KPAD1);
    o[lane] = (uint_t)f2bf(ax0) | ((uint_t)f2bf(ay0) << 16);
    if (two) o[64 + lane] = (uint_t)f2bf(ax1) | ((uint_t)f2bf(ay1) << 16);
}

// ---------------------------------------------------------------------------
// agg for bf16 H (F=384, stride 384) -> bf16 out (stride 384)
// ---------------------------------------------------------------------------
__global__ __launch_bounds__(256) void agg384_kernel(
        const ushort_t* __restrict__ H, const float* __restrict__ dinv,
        const int* __restrict__ ptr, const int* __restrict__ row_srt,
        const float* __restrict__ nrm_srt, ushort_t* __restrict__ out, int N) {
    int w    = (blockIdx.x * blockDim.x + threadIdx.x) >> 6;
    int lane = threadIdx.x & 63;
    if (w >= N) return;
    float d2 = dinv[w]; d2 *= d2;
    const uint_t* self = (const uint_t*)(H + (size_t)w * HIDDEN);
    float ax[3], ay[3];
    #pragma unroll
    for (int j = 0; j < 3; ++j) {
        uint_t u = self[lane + 64 * j];
        ax[j] = bf2f(u & 0xFFFFu) * d2;
        ay[j] = bf2f(u >> 16) * d2;
    }
    int e0 = ptr[w], e1 = ptr[w + 1];
    for (int e = e0; e < e1; ++e) {
        int r = row_srt[e];
        float wg = nrm_srt[e];
        const uint_t* hr = (const uint_t*)(H + (size_t)r * HIDDEN);
        #pragma unroll
        for (int j = 0; j < 3; ++j) {
            uint_t u = hr[lane + 64 * j];
            ax[j] = fmaf(bf2f(u & 0xFFFFu), wg, ax[j]);
            ay[j] = fmaf(bf2f(u >> 16), wg, ay[j]);
        }
    }
    uint_t* o = (uint_t*)(out + (size_t)w * HIDDEN);
    #pragma unroll
    for (int j = 0; j < 3; ++j)
        o[lane + 64 * j] = (uint_t)f2bf(ax[j]) | ((uint_t)f2bf(ay[j]) << 16);
}

// ---------------------------------------------------------------------------
// weight prep: Wt[n][k] = bf16(W[k][n]), zero pad for k >= Kin
// ---------------------------------------------------------------------------
__global__ void prep_wt_kernel(const float* __restrict__ W, ushort_t* __restrict__ Wt,
                               int Kin, int Kpad, int Nn) {
    int idx = blockIdx.x * blockDim.x + threadIdx.x;
    if (idx >= Nn * Kpad) return;
    int n = idx / Kpad, k = idx - n * Kpad;
    float v = (k < Kin) ? W[(size_t)k * Nn + n] : 0.0f;
    Wt[idx] = f2bf(v);
}

// ---------------------------------------------------------------------------
// MFMA bf16 GEMM: C[M_PAD][Nn](bf16) = relu(A[M_PAD][Ks](bf16) @ Wt[Nn][Ks]^T + bias)
// block tile 128x128, BK=32, 4 waves (2x2), wave tile 64x64 = 4x4 frags of 16x16x32
// ---------------------------------------------------------------------------
#define GBK 32

template<bool RELU>
__global__ __launch_bounds__(256) void mfma_gemm_kernel(
        const ushort_t* __restrict__ A, const ushort_t* __restrict__ Wt,
        const float* __restrict__ bias, ushort_t* __restrict__ C,
        int Ks, int Nn) {
    __shared__ ushort_t As[128 * GBK];
    __shared__ ushort_t Bs[128 * GBK];

    const int tid  = threadIdx.x;
    const int lane = tid & 63;
    const int w    = tid >> 6;
    const int wm   = w & 1;
    const int wn   = w >> 1;
    const int bn   = blockIdx.x * 128;
    const int bm   = blockIdx.y * 128;

    const int rA = tid >> 2;       // 0..63
    const int q  = tid & 3;        // 16B chunk (8 bf16) within 64B row

    auto lds_off = [](int row, int chunk) {
        return row * GBK + ((chunk ^ ((row >> 1) & 3)) * 8);   // ushort units
    };
    const int wOff0 = lds_off(rA, q);
    const int wOff1 = lds_off(rA + 64, q);

    auto brow = [](int s) {
        return ((s >> 6) * 64) + ((s & 63) >> 4) + ((s & 15) * 4);
    };
    const int gB0 = brow(rA);
    const int gB1 = brow(rA + 64);

    const ushort_t* Ag0 = A  + (size_t)(bm + rA) * Ks + q * 8;
    const ushort_t* Ag1 = Ag0 + (size_t)64 * Ks;
    const ushort_t* Bg0 = Wt + (size_t)(bn + gB0) * Ks + q * 8;
    const ushort_t* Bg1 = Wt + (size_t)(bn + gB1) * Ks + q * 8;

    const int p     = lane & 15;
    const int khalf = lane >> 4;
    const int qf    = khalf ^ ((p >> 1) & 3);
    int aoff[4], boff[4];
    #pragma unroll
    for (int f = 0; f < 4; ++f) {
        aoff[f] = (wm * 64 + f * 16 + p) * GBK + qf * 8;
        boff[f] = (wn * 64 + f * 16 + p) * GBK + qf * 8;
    }

    f32x4 acc[4][4] = {};

    const int ksteps = Ks >> 5;
    for (int kt = 0; kt < ksteps; ++kt) {
        const int k0 = kt * GBK;
        uint4 va0 = *reinterpret_cast<const uint4*>(Ag0 + k0);
        uint4 va1 = *reinterpret_cast<const uint4*>(Ag1 + k0);
        uint4 vb0 = *reinterpret_cast<const uint4*>(Bg0 + k0);
        uint4 vb1 = *reinterpret_cast<const uint4*>(Bg1 + k0);
        *reinterpret_cast<uint4*>(&As[wOff0]) = va0;
        *reinterpret_cast<uint4*>(&As[wOff1]) = va1;
        *reinterpret_cast<uint4*>(&Bs[wOff0]) = vb0;
        *reinterpret_cast<uint4*>(&Bs[wOff1]) = vb1;
        __syncthreads();

        bf16x8 af[4], bfr[4];
        #pragma unroll
        for (int f = 0; f < 4; ++f) {
            af[f]  = *reinterpret_cast<const bf16x8*>(&As[aoff[f]]);
            bfr[f] = *reinterpret_cast<const bf16x8*>(&Bs[boff[f]]);
        }
        #pragma unroll
        for (int mi = 0; mi < 4; ++mi)
            #pragma unroll
            for (int ni = 0; ni < 4; ++ni)
                acc[mi][ni] = __builtin_amdgcn_mfma_f32_16x16x32_bf16(
                    af[mi], bfr[ni], acc[mi][ni], 0, 0, 0);
        __syncthreads();
    }

    const int colbase = bn + wn * 64 + p * 4;
    const float4 bb = *reinterpret_cast<const float4*>(bias + colbase);
    const float bias4[4] = {bb.x, bb.y, bb.z, bb.w};
    #pragma unroll
    for (int mi = 0; mi < 4; ++mi) {
        const int rowbase = bm + wm * 64 + mi * 16 + khalf * 4;
        #pragma unroll
        for (int j = 0; j < 4; ++j) {
            float v0 = acc[mi][0][j] + bias4[0];
            float v1 = acc[mi][1][j] + bias4[1];
            float v2 = acc[mi][2][j] + bias4[2];
            float v3 = acc[mi][3][j] + bias4[3];
            if (RELU) {
                v0 = fmaxf(v0, 0.f); v1 = fmaxf(v1, 0.f);
                v2 = fmaxf(v2, 0.f); v3 = fmaxf(v3, 0.f);
            }
            ushort4 o;
            o.x = f2bf(v0); o.y = f2bf(v1); o.z = f2bf(v2); o.w = f2bf(v3);
            *reinterpret_cast<ushort4*>(C + (size_t)(rowbase + j) * Nn + colbase) = o;
        }
    }
}

// ---------------------------------------------------------------------------
// G[M,2] = A[M,384](bf16) @ W[384,2](f32) ; wave per row
// ---------------------------------------------------------------------------
__global__ __launch_bounds__(256) void gemm_n2_kernel(
        const ushort_t* __restrict__ A, const float* __restrict__ W,
        float* __restrict__ G, int M) {
    int w    = (blockIdx.x * blockDim.x + threadIdx.x) >> 6;
    int lane = threadIdx.x & 63;
    if (w >= M) return;
    const uint_t* a = (const uint_t*)(A + (size_t)w * HIDDEN);
    float s0 = 0.f, s1 = 0.f;
    #pragma unroll
    for (int j = 0; j < 3; ++j) {
        int f2 = lane + 64 * j;
        uint_t u = a[f2];
        float alo = bf2f(u & 0xFFFFu), ahi = bf2f(u >> 16);
        int k = f2 * 2;
        s0 = fmaf(alo, W[k * 2 + 0], s0);
        s1 = fmaf(alo, W[k * 2 + 1], s1);
        s0 = fmaf(ahi, W[k * 2 + 2], s0);
        s1 = fmaf(ahi, W[k * 2 + 3], s1);
    }
    #pragma unroll
    for (int off = 32; off; off >>= 1) {
        s0 += __shfl_down(s0, off);
        s1 += __shfl_down(s1, off);
    }
    if (lane == 0) { G[(size_t)w * 2] = s0; G[(size_t)w * 2 + 1] = s1; }
}

// ---------------------------------------------------------------------------
// final: out[i,:] = dinv[i]^2*G[i,:] + sum_e nrm_e*G[row_e,:] + b3
// ---------------------------------------------------------------------------
__global__ void out_kernel(const float* __restrict__ G, const float* __restrict__ dinv,
                           const int* __restrict__ ptr, const int* __restrict__ row_srt,
                           const float* __restrict__ nrm_srt, const float* __restrict__ b3,
                           float* __restrict__ out, int N) {
    int i = blockIdx.x * blockDim.x + threadIdx.x;
    if (i >= N) return;
    float d2 = dinv[i]; d2 *= d2;
    float a0 = G[(size_t)i * 2 + 0] * d2 + b3[0];
    float a1 = G[(size_t)i * 2 + 1] * d2 + b3[1];
    int e0 = ptr[i], e1 = ptr[i + 1];
    for (int e = e0; e < e1; ++e) {
        int r = row_srt[e];
        float wg = nrm_srt[e];
        a0 = fmaf(G[(size_t)r * 2 + 0], wg, a0);
        a1 = fmaf(G[(size_t)r * 2 + 1], wg, a1);
    }
    out[(size_t)i * 2 + 0] = a0;
    out[(size_t)i * 2 + 1] = a1;
}

// ---------------------------------------------------------------------------
extern "C" void kernel_launch(void* const* d_in, const int* in_sizes, int n_in,
                              void* d_out, int out_size, void* d_ws, size_t ws_size,
                              hipStream_t stream) {
    const float* x   = (const float*)d_in[0];
    const int*   ei  = (const int*)  d_in[1];   // [2, E]
    const float* W1  = (const float*)d_in[2];
    const float* b1  = (const float*)d_in[3];
    const float* W2  = (const float*)d_in[4];
    const float* b2  = (const float*)d_in[5];
    const float* W3  = (const float*)d_in[6];
    const float* b3  = (const float*)d_in[7];
    float* out = (float*)d_out;

    const int N = N_NODES, E = N_EDGES;
    const int* row = ei;
    const int* col = ei + E;

    // ---- workspace layout (bytes, 256-aligned chunks) ----
    size_t off = 0;
    auto alloc = [&](size_t bytes) { size_t o = off; off += (bytes + 255) & ~(size_t)255; return o; };
    size_t o_dinv   = alloc((size_t)N * 4);
    size_t o_ptr    = alloc((size_t)(N + 1) * 4);
    size_t o_cnt    = alloc((size_t)N * 4);
    size_t o_cursor = alloc((size_t)N * 4);
    size_t o_bsum   = alloc((size_t)NB_SCAN * 4);
    size_t o_rowsrt = alloc((size_t)E * 4);
    size_t o_nrmsrt = alloc((size_t)E * 4);
    size_t o_G      = alloc((size_t)N * 2 * 4);
    size_t o_Wt1    = alloc((size_t)HIDDEN * KPAD1 * 2);
    size_t o_Wt2    = alloc((size_t)HIDDEN * HIDDEN * 2);
    size_t o_B1     = alloc((size_t)M_PAD * HIDDEN * 2);   // bf16: Xa(stride 192) then Ha(384)
    size_t o_B2     = alloc((size_t)M_PAD * HIDDEN * 2);   // bf16: Xb alias, then H1/H2
    if (ws_size < off) return;   // visible zero-output failure if too small

    char* ws = (char*)d_ws;
    float*    dinv    = (float*)(ws + o_dinv);
    int*      ptr     = (int*)  (ws + o_ptr);
    int*      cnt     = (int*)  (ws + o_cnt);
    int*      cursor  = (int*)  (ws + o_cursor);
    int*      bsum    = (int*)  (ws + o_bsum);
    int*      row_srt = (int*)  (ws + o_rowsrt);
    float*    nrm_srt = (float*)(ws + o_nrmsrt);
    float*    G       = (float*)(ws + o_G);
    ushort_t* Wt1     = (ushort_t*)(ws + o_Wt1);
    ushort_t* Wt2     = (ushort_t*)(ws + o_Wt2);
    ushort_t* B1      = (ushort_t*)(ws + o_B1);
    ushort_t* B2      = (ushort_t*)(ws + o_B2);
    uint_t*   Xb      = (uint_t*)B2;   // bf16 X, [N][96] uints; dead once GEMM1 writes H1

    const int B = 256;

    // 0. weight prep (bf16 transpose, zero-padded K) + X bf16 conversion
    prep_wt_kernel<<<(HIDDEN * KPAD1 + B - 1) / B, B, 0, stream>>>(W1, Wt1, F_IN, KPAD1, HIDDEN);
    prep_wt_kernel<<<(HIDDEN * HIDDEN + B - 1) / B, B, 0, stream>>>(W2, Wt2, HIDDEN, HIDDEN, HIDDEN);
    convx_kernel<<<(N * 96 + B - 1) / B, B, 0, stream>>>(x, Xb, N * 96);

    // 1. CSR build + dinv (two-level parallel scan)
    hipMemsetAsync(cnt, 0, (size_t)N * 4, stream);
    count_kernel<<<(E + B - 1) / B, B, 0, stream>>>(col, cnt, E);
    dinv_kernel<<<(N + B - 1) / B, B, 0, stream>>>(cnt, dinv, N);
    scan1_kernel<<<NB_SCAN, 256, 0, stream>>>(cnt, ptr, bsum, N);
    scan2_kernel<<<1, 1024, 0, stream>>>(bsum, NB_SCAN);
    scan3_kernel<<<NB_SCAN, 256, 0, stream>>>(ptr, cursor, bsum, N, E);
    scatter_kernel<<<(E + B - 1) / B, B, 0, stream>>>(row, col, dinv, cursor, row_srt, nrm_srt, E);

    // 2. Xa = A @ Xb -> B1 (bf16, stride KPAD1); 6-line aligned gathers
    agg165b_kernel<<<(N * 64 + B - 1) / B, B, 0, stream>>>(Xb, dinv, ptr, row_srt, nrm_srt, B1, N);

    // 3. H1 = relu(Xa @ W1 + b1) -> B2 (overwrites Xb, which is now dead)
    {
        dim3 grid(HIDDEN / 128, M_TILES);
        mfma_gemm_kernel<true><<<grid, 256, 0, stream>>>(B1, Wt1, b1, B2, KPAD1, HIDDEN);
    }

    // 4. Ha = A @ H1 -> B1 (stride 384)
    agg384_kernel<<<(N * 64 + B - 1) / B, B, 0, stream>>>(B2, dinv, ptr, row_srt, nrm_srt, B1, N);

    // 5. H2 = relu(Ha @ W2 + b2) -> B2
    {
        dim3 grid(HIDDEN / 128, M_TILES);
        mfma_gemm_kernel<true><<<grid, 256, 0, stream>>>(B1, Wt2, b2, B2, HIDDEN, HIDDEN);
    }

    // 6. G = H2 @ W3 (N x 2, fp32)
    gemm_n2_kernel<<<(N * 64 + B - 1) / B, B, 0, stream>>>(B2, W3, G, N);

    // 7. out = A @ G + b3
    out_kernel<<<(N + B - 1) / B, B, 0, stream>>>(G, dinv, ptr, row_srt, nrm_srt, b3, out, N);
}

// Round 10
// 508.426 us; speedup vs baseline: 4.2162x; 1.0617x over previous
//
#include <hip/hip_runtime.h>
#include <hip/hip_bf16.h>

#define N_NODES 200000
#define N_EDGES 500000
#define F_IN    165
#define HIDDEN  384
#define F_OUT   2

#define KPAD1   192          // F_IN padded to multiple of 32
#define M_TILES 1563         // ceil(200000/128)
#define M_PAD   (M_TILES * 128)
#define NB_SCAN 782          // ceil(200000/256)
#define GRID_GEMM (196 * 24) // ceil(1563/8) groups * (3 cols * 8 panels)

typedef unsigned short ushort_t;
typedef unsigned int   uint_t;

using bf16x8 = __attribute__((ext_vector_type(8))) short;
using f32x4  = __attribute__((ext_vector_type(4))) float;

__device__ __forceinline__ float bf2f(uint_t u) {
    return __uint_as_float(u << 16);
}
__device__ __forceinline__ ushort_t f2bf(float x) {
    uint_t b = __float_as_uint(x);
    return (ushort_t)((b + 0x7FFFu + ((b >> 16) & 1u)) >> 16);  // RNE
}

// ---------------------------------------------------------------------------
// degree count (in-degree via col), int atomics into `cnt`
// ---------------------------------------------------------------------------
__global__ void count_kernel(const int* __restrict__ col, int* __restrict__ cnt, int E) {
    int e = blockIdx.x * blockDim.x + threadIdx.x;
    if (e < E) atomicAdd(&cnt[col[e]], 1);
}

__global__ void dinv_kernel(const int* __restrict__ cnt, float* __restrict__ dinv, int n) {
    int i = blockIdx.x * blockDim.x + threadIdx.x;
    if (i < n) dinv[i] = rsqrtf((float)(cnt[i] + 1));   // +1 self loop
}

// ---------------------------------------------------------------------------
// two-level exclusive scan of cnt[0..N) -> ptr (local prefix), bsum (block sums)
// ---------------------------------------------------------------------------
__global__ __launch_bounds__(256) void scan1_kernel(const int* __restrict__ cnt,
                                                    int* __restrict__ loc,
                                                    int* __restrict__ bsum, int N) {
    __shared__ int sh[256];
    int t = threadIdx.x;
    int i = blockIdx.x * 256 + t;
    int v = (i < N) ? cnt[i] : 0;
    sh[t] = v;
    __syncthreads();
    #pragma unroll
    for (int off = 1; off < 256; off <<= 1) {
        int u = (t >= off) ? sh[t - off] : 0;
        __syncthreads();
        sh[t] += u;
        __syncthreads();
    }
    int incl = sh[t];
    if (i < N) loc[i] = incl - v;            // exclusive local prefix
    if (t == 255) bsum[blockIdx.x] = incl;   // block total
}

__global__ __launch_bounds__(1024) void scan2_kernel(int* __restrict__ bsum, int NB) {
    __shared__ int sh[1024];
    int t = threadIdx.x;
    int v = (t < NB) ? bsum[t] : 0;
    sh[t] = v;
    __syncthreads();
    #pragma unroll
    for (int off = 1; off < 1024; off <<= 1) {
        int u = (t >= off) ? sh[t - off] : 0;
        __syncthreads();
        sh[t] += u;
        __syncthreads();
    }
    if (t < NB) bsum[t] = sh[t] - v;         // exclusive
}

__global__ __launch_bounds__(256) void scan3_kernel(int* __restrict__ ptr,
                                                    int* __restrict__ cursor,
                                                    const int* __restrict__ bsum,
                                                    int N, int E) {
    int t = threadIdx.x;
    int i = blockIdx.x * 256 + t;
    if (i < N) {
        int p = ptr[i] + bsum[blockIdx.x];
        ptr[i] = p;
        cursor[i] = p;
    }
    if (i == 0) ptr[N] = E;
}

// ---------------------------------------------------------------------------
// scatter edges into CSR-by-col order; nrm = dinv[r]*dinv[c]
// ---------------------------------------------------------------------------
__global__ void scatter_kernel(const int* __restrict__ row, const int* __restrict__ col,
                               const float* __restrict__ dinv,
                               int* __restrict__ cursor,
                               int* __restrict__ row_srt, float* __restrict__ nrm_srt, int E) {
    int e = blockIdx.x * blockDim.x + threadIdx.x;
    if (e >= E) return;
    int r = row[e], c = col[e];
    int pos = atomicAdd(&cursor[c], 1);
    row_srt[pos] = r;
    nrm_srt[pos] = dinv[r] * dinv[c];
}

// ---------------------------------------------------------------------------
// convert X fp32 [N][165] -> bf16 [N][192] (zero pad), rows 64B-aligned.
// ---------------------------------------------------------------------------
__global__ void convx_kernel(const float* __restrict__ X, uint_t* __restrict__ Xb, int total) {
    int idx = blockIdx.x * blockDim.x + threadIdx.x;   // over N*96
    if (idx >= total) return;
    int node = idx / 96, ui = idx - node * 96;
    int f = ui * 2;
    const float* xr = X + (size_t)node * F_IN;
    float lo = (f < F_IN) ? xr[f] : 0.0f;
    float hi = (f + 1 < F_IN) ? xr[f + 1] : 0.0f;
    Xb[idx] = (uint_t)f2bf(lo) | ((uint_t)f2bf(hi) << 16);
}

// ---------------------------------------------------------------------------
// agg for bf16 X (stride 96 uints) -> bf16 out, stride KPAD1. wave per node.
// ---------------------------------------------------------------------------
__global__ __launch_bounds__(256) void agg165b_kernel(
        const uint_t* __restrict__ Xb, const float* __restrict__ dinv,
        const int* __restrict__ ptr, const int* __restrict__ row_srt,
        const float* __restrict__ nrm_srt, ushort_t* __restrict__ out, int N) {
    int w    = (blockIdx.x * blockDim.x + threadIdx.x) >> 6;
    int lane = threadIdx.x & 63;
    if (w >= N) return;
    float d2 = dinv[w]; d2 *= d2;
    const uint_t* self = Xb + (size_t)w * 96;
    bool two = (lane < 19);                    // uints 64..82 cover f 128..165
    uint_t u0 = self[lane];
    uint_t u1 = two ? self[64 + lane] : 0u;
    float ax0 = bf2f(u0 & 0xFFFFu) * d2, ay0 = bf2f(u0 >> 16) * d2;
    float ax1 = bf2f(u1 & 0xFFFFu) * d2, ay1 = bf2f(u1 >> 16) * d2;
    int e0 = ptr[w], e1 = ptr[w + 1];
    for (int e = e0; e < e1; ++e) {
        int r = row_srt[e];
        float wg = nrm_srt[e];
        const uint_t* hr = Xb + (size_t)r * 96;
        uint_t v0 = hr[lane];
        uint_t v1 = two ? hr[64 + lane] : 0u;
        ax0 = fmaf(bf2f(v0 & 0xFFFFu), wg, ax0);
        ay0 = fmaf(bf2f(v0 >> 16), wg, ay0);
        ax1 = fmaf(bf2f(v1 & 0xFFFFu), wg, ax1);
        ay1 = fmaf(bf2f(v1 >> 16), wg, ay1);
    }
    uint_t* o = (uint_t*)(out + (size_t)w * KPAD1);
    o[lane] = (uint_t)f2bf(ax0) | ((uint_t)f2bf(ay0) << 16);
    if (two) o[64 + lane] = (uint_t)f2bf(ax1) | ((uint_t)f2bf(ay1) << 16);
}

// ---------------------------------------------------------------------------
// agg for bf16 H (F=384, stride 384) -> bf16 out (stride 384)
// ---------------------------------------------------------------------------
__global__ __launch_bounds__(256) void agg384_kernel(
        const ushort_t* __restrict__ H, const float* __restrict__ dinv,
        const int* __restrict__ ptr, const int* __restrict__ row_srt,
        const float* __restrict__ nrm_srt, ushort_t* __restrict__ out, int N) {
    int w    = (blockIdx.x * blockDim.x + threadIdx.x) >> 6;
    int lane = threadIdx.x & 63;
    if (w >= N) return;
    float d2 = dinv[w]; d2 *= d2;
    const uint_t* self = (const uint_t*)(H + (size_t)w * HIDDEN);
    float ax[3], ay[3];
    #pragma unroll
    for (int j = 0; j < 3; ++j) {
        uint_t u = self[lane + 64 * j];
        ax[j] = bf2f(u & 0xFFFFu) * d2;
        ay[j] = bf2f(u >> 16) * d2;
    }
    int e0 = ptr[w], e1 = ptr[w + 1];
    for (int e = e0; e < e1; ++e) {
        int r = row_srt[e];
        float wg = nrm_srt[e];
        const uint_t* hr = (const uint_t*)(H + (size_t)r * HIDDEN);
        #pragma unroll
        for (int j = 0; j < 3; ++j) {
            uint_t u = hr[lane + 64 * j];
            ax[j] = fmaf(bf2f(u & 0xFFFFu), wg, ax[j]);
            ay[j] = fmaf(bf2f(u >> 16), wg, ay[j]);
        }
    }
    uint_t* o = (uint_t*)(out + (size_t)w * HIDDEN);
    #pragma unroll
    for (int j = 0; j < 3; ++j)
        o[lane + 64 * j] = (uint_t)f2bf(ax[j]) | ((uint_t)f2bf(ay[j]) << 16);
}

// ---------------------------------------------------------------------------
// weight prep: Wt[n][k] = bf16(W[k][n]), zero pad for k >= Kin
// ---------------------------------------------------------------------------
__global__ void prep_wt_kernel(const float* __restrict__ W, ushort_t* __restrict__ Wt,
                               int Kin, int Kpad, int Nn) {
    int idx = blockIdx.x * blockDim.x + threadIdx.x;
    if (idx >= Nn * Kpad) return;
    int n = idx / Kpad, k = idx - n * Kpad;
    float v = (k < Kin) ? W[(size_t)k * Nn + n] : 0.0f;
    Wt[idx] = f2bf(v);
}

// ---------------------------------------------------------------------------
// MFMA bf16 GEMM: C[M_PAD][384](bf16) = relu(A @ Wt^T + bias)
// block tile 128x128, BK=32, 4 waves (2x2), wave tile 64x64.
// 1D grid, XCD-coherent swizzle: l = g*24 + c*8 + pm -> the 3 col-blocks of a
// panel share l%8 (same XCD on round-robin dispatch) => A panel hits one L2.
// K-loop: register-prefetch double buffer (issue next-tile loads under MFMA).
// ---------------------------------------------------------------------------
#define GBK 32

template<bool RELU>
__global__ __launch_bounds__(256) void mfma_gemm_kernel(
        const ushort_t* __restrict__ A, const ushort_t* __restrict__ Wt,
        const float* __restrict__ bias, ushort_t* __restrict__ C,
        int Ks, int Nn, int nTilesM) {
    __shared__ ushort_t As[128 * GBK];
    __shared__ ushort_t Bs[128 * GBK];

    // ---- swizzled block -> (panel, col) ----
    const int l  = blockIdx.x;
    const int g  = l / 24;
    const int r_ = l - g * 24;
    const int cb = r_ >> 3;
    const int pm = r_ & 7;
    const int pt = g * 8 + pm;
    if (pt >= nTilesM) return;
    const int bm = pt * 128;
    const int bn = cb * 128;

    const int tid  = threadIdx.x;
    const int lane = tid & 63;
    const int w    = tid >> 6;
    const int wm   = w & 1;
    const int wn   = w >> 1;

    const int rA = tid >> 2;       // 0..63
    const int q  = tid & 3;        // 16B chunk (8 bf16) within 64B row

    auto lds_off = [](int row, int chunk) {
        return row * GBK + ((chunk ^ ((row >> 1) & 3)) * 8);   // ushort units
    };
    const int wOff0 = lds_off(rA, q);
    const int wOff1 = lds_off(rA + 64, q);

    auto brow = [](int s) {
        return ((s >> 6) * 64) + ((s & 63) >> 4) + ((s & 15) * 4);
    };
    const int gB0 = brow(rA);
    const int gB1 = brow(rA + 64);

    const ushort_t* Ag0 = A  + (size_t)(bm + rA) * Ks + q * 8;
    const ushort_t* Ag1 = Ag0 + (size_t)64 * Ks;
    const ushort_t* Bg0 = Wt + (size_t)(bn + gB0) * Ks + q * 8;
    const ushort_t* Bg1 = Wt + (size_t)(bn + gB1) * Ks + q * 8;

    const int p     = lane & 15;
    const int khalf = lane >> 4;
    const int qf    = khalf ^ ((p >> 1) & 3);
    int aoff[4], boff[4];
    #pragma unroll
    for (int f = 0; f < 4; ++f) {
        aoff[f] = (wm * 64 + f * 16 + p) * GBK + qf * 8;
        boff[f] = (wn * 64 + f * 16 + p) * GBK + qf * 8;
    }

    f32x4 acc[4][4] = {};

    const int ksteps = Ks >> 5;
    // prologue: load K-tile 0 into registers
    uint4 va0 = *reinterpret_cast<const uint4*>(Ag0);
    uint4 va1 = *reinterpret_cast<const uint4*>(Ag1);
    uint4 vb0 = *reinterpret_cast<const uint4*>(Bg0);
    uint4 vb1 = *reinterpret_cast<const uint4*>(Bg1);

    for (int kt = 0; kt < ksteps; ++kt) {
        __syncthreads();   // prev-iter LDS reads done
        *reinterpret_cast<uint4*>(&As[wOff0]) = va0;
        *reinterpret_cast<uint4*>(&As[wOff1]) = va1;
        *reinterpret_cast<uint4*>(&Bs[wOff0]) = vb0;
        *reinterpret_cast<uint4*>(&Bs[wOff1]) = vb1;
        __syncthreads();   // LDS ready

        if (kt + 1 < ksteps) {   // issue next-tile loads; land under MFMA
            const int k0 = (kt + 1) * GBK;
            va0 = *reinterpret_cast<const uint4*>(Ag0 + k0);
            va1 = *reinterpret_cast<const uint4*>(Ag1 + k0);
            vb0 = *reinterpret_cast<const uint4*>(Bg0 + k0);
            vb1 = *reinterpret_cast<const uint4*>(Bg1 + k0);
        }

        bf16x8 af[4], bfr[4];
        #pragma unroll
        for (int f = 0; f < 4; ++f) {
            af[f]  = *reinterpret_cast<const bf16x8*>(&As[aoff[f]]);
            bfr[f] = *reinterpret_cast<const bf16x8*>(&Bs[boff[f]]);
        }
        #pragma unroll
        for (int mi = 0; mi < 4; ++mi)
            #pragma unroll
            for (int ni = 0; ni < 4; ++ni)
                acc[mi][ni] = __builtin_amdgcn_mfma_f32_16x16x32_bf16(
                    af[mi], bfr[ni], acc[mi][ni], 0, 0, 0);
    }

    const int colbase = bn + wn * 64 + p * 4;
    const float4 bb = *reinterpret_cast<const float4*>(bias + colbase);
    const float bias4[4] = {bb.x, bb.y, bb.z, bb.w};
    #pragma unroll
    for (int mi = 0; mi < 4; ++mi) {
        const int rowbase = bm + wm * 64 + mi * 16 + khalf * 4;
        #pragma unroll
        for (int j = 0; j < 4; ++j) {
            float v0 = acc[mi][0][j] + bias4[0];
            float v1 = acc[mi][1][j] + bias4[1];
            float v2 = acc[mi][2][j] + bias4[2];
            float v3 = acc[mi][3][j] + bias4[3];
            if (RELU) {
                v0 = fmaxf(v0, 0.f); v1 = fmaxf(v1, 0.f);
                v2 = fmaxf(v2, 0.f); v3 = fmaxf(v3, 0.f);
            }
            ushort4 o;
            o.x = f2bf(v0); o.y = f2bf(v1); o.z = f2bf(v2); o.w = f2bf(v3);
            *reinterpret_cast<ushort4*>(C + (size_t)(rowbase + j) * Nn + colbase) = o;
        }
    }
}

// ---------------------------------------------------------------------------
// G[M,2] = A[M,384](bf16) @ W[384,2](f32) ; wave per row
// ---------------------------------------------------------------------------
__global__ __launch_bounds__(256) void gemm_n2_kernel(
        const ushort_t* __restrict__ A, const float* __restrict__ W,
        float* __restrict__ G, int M) {
    int w    = (blockIdx.x * blockDim.x + threadIdx.x) >> 6;
    int lane = threadIdx.x & 63;
    if (w >= M) return;
    const uint_t* a = (const uint_t*)(A + (size_t)w * HIDDEN);
    float s0 = 0.f, s1 = 0.f;
    #pragma unroll
    for (int j = 0; j < 3; ++j) {
        int f2 = lane + 64 * j;
        uint_t u = a[f2];
        float alo = bf2f(u & 0xFFFFu), ahi = bf2f(u >> 16);
        int k = f2 * 2;
        s0 = fmaf(alo, W[k * 2 + 0], s0);
        s1 = fmaf(alo, W[k * 2 + 1], s1);
        s0 = fmaf(ahi, W[k * 2 + 2], s0);
        s1 = fmaf(ahi, W[k * 2 + 3], s1);
    }
    #pragma unroll
    for (int off = 32; off; off >>= 1) {
        s0 += __shfl_down(s0, off);
        s1 += __shfl_down(s1, off);
    }
    if (lane == 0) { G[(size_t)w * 2] = s0; G[(size_t)w * 2 + 1] = s1; }
}

// ---------------------------------------------------------------------------
// final: out[i,:] = dinv[i]^2*G[i,:] + sum_e nrm_e*G[row_e,:] + b3
// ---------------------------------------------------------------------------
__global__ void out_kernel(const float* __restrict__ G, const float* __restrict__ dinv,
                           const int* __restrict__ ptr, const int* __restrict__ row_srt,
                           const float* __restrict__ nrm_srt, const float* __restrict__ b3,
                           float* __restrict__ out, int N) {
    int i = blockIdx.x * blockDim.x + threadIdx.x;
    if (i >= N) return;
    float d2 = dinv[i]; d2 *= d2;
    float a0 = G[(size_t)i * 2 + 0] * d2 + b3[0];
    float a1 = G[(size_t)i * 2 + 1] * d2 + b3[1];
    int e0 = ptr[i], e1 = ptr[i + 1];
    for (int e = e0; e < e1; ++e) {
        int r = row_srt[e];
        float wg = nrm_srt[e];
        a0 = fmaf(G[(size_t)r * 2 + 0], wg, a0);
        a1 = fmaf(G[(size_t)r * 2 + 1], wg, a1);
    }
    out[(size_t)i * 2 + 0] = a0;
    out[(size_t)i * 2 + 1] = a1;
}

// ---------------------------------------------------------------------------
extern "C" void kernel_launch(void* const* d_in, const int* in_sizes, int n_in,
                              void* d_out, int out_size, void* d_ws, size_t ws_size,
                              hipStream_t stream) {
    const float* x   = (const float*)d_in[0];
    const int*   ei  = (const int*)  d_in[1];   // [2, E]
    const float* W1  = (const float*)d_in[2];
    const float* b1  = (const float*)d_in[3];
    const float* W2  = (const float*)d_in[4];
    const float* b2  = (const float*)d_in[5];
    const float* W3  = (const float*)d_in[6];
    const float* b3  = (const float*)d_in[7];
    float* out = (float*)d_out;

    const int N = N_NODES, E = N_EDGES;
    const int* row = ei;
    const int* col = ei + E;

    // ---- workspace layout (bytes, 256-aligned chunks) ----
    size_t off = 0;
    auto alloc = [&](size_t bytes) { size_t o = off; off += (bytes + 255) & ~(size_t)255; return o; };
    size_t o_dinv   = alloc((size_t)N * 4);
    size_t o_ptr    = alloc((size_t)(N + 1) * 4);
    size_t o_cnt    = alloc((size_t)N * 4);
    size_t o_cursor = alloc((size_t)N * 4);
    size_t o_bsum   = alloc((size_t)NB_SCAN * 4);
    size_t o_rowsrt = alloc((size_t)E * 4);
    size_t o_nrmsrt = alloc((size_t)E * 4);
    size_t o_G      = alloc((size_t)N * 2 * 4);
    size_t o_Wt1    = alloc((size_t)HIDDEN * KPAD1 * 2);
    size_t o_Wt2    = alloc((size_t)HIDDEN * HIDDEN * 2);
    size_t o_B1     = alloc((size_t)M_PAD * HIDDEN * 2);   // bf16: Xa(stride 192) then Ha(384)
    size_t o_B2     = alloc((size_t)M_PAD * HIDDEN * 2);   // bf16: Xb alias, then H1/H2
    if (ws_size < off) return;   // visible zero-output failure if too small

    char* ws = (char*)d_ws;
    float*    dinv    = (float*)(ws + o_dinv);
    int*      ptr     = (int*)  (ws + o_ptr);
    int*      cnt     = (int*)  (ws + o_cnt);
    int*      cursor  = (int*)  (ws + o_cursor);
    int*      bsum    = (int*)  (ws + o_bsum);
    int*      row_srt = (int*)  (ws + o_rowsrt);
    float*    nrm_srt = (float*)(ws + o_nrmsrt);
    float*    G       = (float*)(ws + o_G);
    ushort_t* Wt1     = (ushort_t*)(ws + o_Wt1);
    ushort_t* Wt2     = (ushort_t*)(ws + o_Wt2);
    ushort_t* B1      = (ushort_t*)(ws + o_B1);
    ushort_t* B2      = (ushort_t*)(ws + o_B2);
    uint_t*   Xb      = (uint_t*)B2;   // bf16 X, [N][96] uints; dead once GEMM1 writes H1

    const int B = 256;

    // 0. weight prep (bf16 transpose, zero-padded K) + X bf16 conversion
    prep_wt_kernel<<<(HIDDEN * KPAD1 + B - 1) / B, B, 0, stream>>>(W1, Wt1, F_IN, KPAD1, HIDDEN);
    prep_wt_kernel<<<(HIDDEN * HIDDEN + B - 1) / B, B, 0, stream>>>(W2, Wt2, HIDDEN, HIDDEN, HIDDEN);
    convx_kernel<<<(N * 96 + B - 1) / B, B, 0, stream>>>(x, Xb, N * 96);

    // 1. CSR build + dinv (two-level parallel scan)
    hipMemsetAsync(cnt, 0, (size_t)N * 4, stream);
    count_kernel<<<(E + B - 1) / B, B, 0, stream>>>(col, cnt, E);
    dinv_kernel<<<(N + B - 1) / B, B, 0, stream>>>(cnt, dinv, N);
    scan1_kernel<<<NB_SCAN, 256, 0, stream>>>(cnt, ptr, bsum, N);
    scan2_kernel<<<1, 1024, 0, stream>>>(bsum, NB_SCAN);
    scan3_kernel<<<NB_SCAN, 256, 0, stream>>>(ptr, cursor, bsum, N, E);
    scatter_kernel<<<(E + B - 1) / B, B, 0, stream>>>(row, col, dinv, cursor, row_srt, nrm_srt, E);

    // 2. Xa = A @ Xb -> B1 (bf16, stride KPAD1); 6-line aligned gathers
    agg165b_kernel<<<(N * 64 + B - 1) / B, B, 0, stream>>>(Xb, dinv, ptr, row_srt, nrm_srt, B1, N);

    // 3. H1 = relu(Xa @ W1 + b1) -> B2 (overwrites Xb, which is now dead)
    mfma_gemm_kernel<true><<<GRID_GEMM, 256, 0, stream>>>(B1, Wt1, b1, B2, KPAD1, HIDDEN, M_TILES);

    // 4. Ha = A @ H1 -> B1 (stride 384)
    agg384_kernel<<<(N * 64 + B - 1) / B, B, 0, stream>>>(B2, dinv, ptr, row_srt, nrm_srt, B1, N);

    // 5. H2 = relu(Ha @ W2 + b2) -> B2
    mfma_gemm_kernel<true><<<GRID_GEMM, 256, 0, stream>>>(B1, Wt2, b2, B2, HIDDEN, HIDDEN, M_TILES);

    // 6. G = H2 @ W3 (N x 2, fp32)
    gemm_n2_kernel<<<(N * 64 + B - 1) / B, B, 0, stream>>>(B2, W3, G, N);

    // 7. out = A @ G + b3
    out_kernel<<<(N + B - 1) / B, B, 0, stream>>>(G, dinv, ptr, row_srt, nrm_srt, b3, out, N);
}